// Round 7
// baseline (339.939 us; speedup 1.0000x reference)
//
#include <hip/hip_runtime.h>
#include <float.h>

// EdgeConv: B=4, N=4096, Fin=64, Fout=64, K=20
// out[b,n,o] = u[b,n,o] + max_{m in knn20(n)} v[b,m,o]
//   u = x.(W1-W2)^T + bias ; v = x.W2^T
// knn on d = sq[n] + sq[m] - 2 x_n.x_m (>=0), self excluded.
//
// R13: fused scheme (R12-verified numerics) re-shaped for the REAL
// register budget. Evidence: 512-thread blocks got VGPR_Count=128 from
// the compiler in BOTH R10 and R12 regardless of __launch_bounds__,
// spilling ~80 regs/lane (R12: WRITE 70 MB = 64 MB scratch, 193 us).
// 256-thread kernels always got what they needed. So: 256-thread block
// (4 waves) = 32 n-rows x 1024 m (a QUARTER), launch_bounds(256,2)
// -> 256-VGPR cap, peak live ~190, no spill. Per wave 256 m over 8
// j-tiles, kpk[8][8] = 64 VGPRs. Grid 2048. Each (row,quarter) writes
// an exact-top-20 (ds||m) shortlist (union over quarters is a superset
// of the global top-20); merge rank-selects the exact global top-20
// from 80 entries, gathers v, writes out. Output identical to R8/R9/R12.

constexpr int Bb = 4, Nn = 4096, Ff = 64, Kk = 20;

typedef __attribute__((ext_vector_type(8))) short bf16x8;
typedef __attribute__((ext_vector_type(16))) float f32x16;

__device__ inline unsigned int bf16rn(float f) {
  unsigned int u = __float_as_uint(f);
  return (u + 0x7fffu + ((u >> 16) & 1u)) >> 16;
}

// ---------------- K1: u, v, sq, xhi, xlo (swizzled) ----------------
constexpr int RT1 = 16;  // rows per block

__global__ __launch_bounds__(256) void uv_kernel2(
    const float* __restrict__ x, const float* __restrict__ W,
    const float* __restrict__ bvec, float* __restrict__ u,
    float* __restrict__ v, float* __restrict__ sq,
    unsigned short* __restrict__ xhi, unsigned short* __restrict__ xlo) {
  __shared__ __align__(16) float4 Ws[64 * 33];   // W row o at granules [33o,33o+32)
  __shared__ __align__(16) float4 xs[RT1 * 16];  // x row r at [16r..)
  const int t = threadIdx.x, l = t & 63, w = t >> 6;
  const int bn0 = blockIdx.x * RT1;
  #pragma unroll
  for (int i = 0; i < 8; i++) {
    int f = t + 256 * i;  // f4 index into W (64 rows x 32 f4)
    Ws[(f >> 5) * 33 + (f & 31)] = ((const float4*)W)[f];
  }
  xs[t] = ((const float4*)x)[bn0 * 16 + t];
  __syncthreads();
  // bf16 hi/lo split -> MFMA-fragment-swizzled layout
  #pragma unroll
  for (int i = 0; i < 4; i++) {
    int idx = t + 256 * i;   // 0..1023 within block's 16 rows
    int nloc = idx >> 6;     // row within block
    int k = idx & 63;        // channel
    float val = ((const float*)xs)[idx];
    unsigned int hb = bf16rn(val);
    float fhi = __uint_as_float(hb << 16);
    unsigned int lb = bf16rn(val - fhi);
    int ng = bn0 + nloc;  // global flat row (batch-local swizzle folds in)
    size_t flat = ((size_t)(ng >> 5) << 11) + ((size_t)(k >> 4) << 9) +
                  ((size_t)((k >> 3) & 1) << 8) + ((size_t)(ng & 31) << 3) +
                  (size_t)(k & 7);
    xhi[flat] = (unsigned short)hb;
    xlo[flat] = (unsigned short)lb;
  }
  // sq for rows 4w..4w+3
  #pragma unroll
  for (int i = 0; i < 4; i++) {
    int r = 4 * w + i;
    float val = ((const float*)&xs[r * 16])[l];
    float s = val * val;
    #pragma unroll
    for (int d = 32; d; d >>= 1) s += __shfl_xor(s, d, 64);
    if (l == 0) sq[bn0 + r] = s;
  }
  const int o = l;
  float ua[4] = {0.f, 0.f, 0.f, 0.f}, va[4] = {0.f, 0.f, 0.f, 0.f};
  #pragma unroll
  for (int c = 0; c < 16; c++) {
    float4 w1 = Ws[o * 33 + c];
    float4 w2 = Ws[o * 33 + 16 + c];
    float4 wd;
    wd.x = w1.x - w2.x; wd.y = w1.y - w2.y;
    wd.z = w1.z - w2.z; wd.w = w1.w - w2.w;
    #pragma unroll
    for (int i = 0; i < 4; i++) {
      float4 xv = xs[(4 * w + i) * 16 + c];
      ua[i] += xv.x * wd.x + xv.y * wd.y + xv.z * wd.z + xv.w * wd.w;
      va[i] += xv.x * w2.x + xv.y * w2.y + xv.z * w2.z + xv.w * w2.w;
    }
  }
  float bo = bvec[o];
  #pragma unroll
  for (int i = 0; i < 4; i++) {
    size_t row = (size_t)(bn0 + 4 * w + i);
    u[row * 64 + o] = ua[i] + bo;
    v[row * 64 + o] = va[i];
  }
}

// ---------------- fused quarter-kernel: keys in regs, shortlist out -----
// Grid 2048 (= Bb * 128 n-tiles * 4 m-quarters). Block 256 thr = 4 waves.
// Wave w: m in [mq*1024 + 256w .. +256) over 8 j-tiles of 32.
// C/D: col=lane&31, row=(reg&3)+8*(reg>>2)+4*(lane>>5) [m74/m101].
// Per lane 128 keys packed in 64 VGPRs (static idx only).

__global__ __launch_bounds__(256, 2) void quarter_knn_kernel(
    const float* __restrict__ x, const unsigned short* __restrict__ xhi,
    const unsigned short* __restrict__ xlo, const float* __restrict__ sq,
    unsigned long long* __restrict__ shortl) {
  __shared__ unsigned int histS[32 * 129];  // stride 129: bank=(row+bin)&31
  __shared__ int candS[32][64];
  __shared__ unsigned int rowminS[32];
  __shared__ unsigned int cntS[32];
  __shared__ unsigned int hcS[32];
  __shared__ unsigned int fbS;
  __shared__ unsigned long long keyS[4][64];

  const int t = threadIdx.x, l = t & 63, w = t >> 6;  // w in [0,4)
  const int blk = blockIdx.x;       // 0..2047
  const int b = blk >> 9;           // batch
  const int r = blk & 511;
  const int n_base = (r >> 2) * 32;
  const int mq = r & 3;
  const int m0w = mq * 1024 + w * 256;
  const int col = l & 31, hoff = (l >> 5) * 4;

  if (t < 32) { rowminS[t] = 0xFFFFFFFFu; cntS[t] = 0u; }
  if (t == 0) fbS = 0u;
  #pragma unroll
  for (int i = 0; i < 16; i++) histS[t + 256 * i] = 0u;
  if (t < 32) histS[4096 + t] = 0u;  // tail: 32*129-4096 = 32 entries

  const unsigned short* xhb = xhi + (size_t)b * Nn * Ff;
  const unsigned short* xlb = xlo + (size_t)b * Nn * Ff;
  const float* sqb = sq + b * Nn;

  // A fragments (32 rows x 64 ch, hi/lo)
  bf16x8 Ahi[4], Alo[4];
  #pragma unroll
  for (int ks = 0; ks < 4; ks++) {
    size_t off = ((size_t)((n_base >> 5) * 4 + ks) << 9) + ((size_t)l << 3);
    Ahi[ks] = *(const bf16x8*)(xhb + off);
    Alo[ks] = *(const bf16x8*)(xlb + off);
  }
  float sqn_r[16];
  #pragma unroll
  for (int e = 0; e < 16; e++)
    sqn_r[e] = sqb[n_base + (e & 3) + 8 * (e >> 2) + hoff];
  __syncthreads();  // LDS init complete before any atomics

  // ---- pass 1: MFMA sweep; 128 16-bit keys/lane into 64 VGPRs ----
  unsigned int kpk[8][8];  // [j][e>>1]: lo = e even, hi = e odd (STATIC)
  unsigned int kmin[16];
  #pragma unroll
  for (int e = 0; e < 16; e++) kmin[e] = 0xFFFFFFFFu;

  #pragma unroll
  for (int j = 0; j < 8; ++j) {
    const int m0 = m0w + 32 * j;
    const int mblk = m0 >> 5;
    bf16x8 Bhi[4], Blo[4];
    #pragma unroll
    for (int ks = 0; ks < 4; ks++) {
      size_t off = ((size_t)(mblk * 4 + ks) << 9) + ((size_t)l << 3);
      Bhi[ks] = *(const bf16x8*)(xhb + off);
      Blo[ks] = *(const bf16x8*)(xlb + off);
    }
    f32x16 acc = {0.f, 0.f, 0.f, 0.f, 0.f, 0.f, 0.f, 0.f,
                  0.f, 0.f, 0.f, 0.f, 0.f, 0.f, 0.f, 0.f};
    #pragma unroll
    for (int ks = 0; ks < 4; ks++) {
      acc = __builtin_amdgcn_mfma_f32_32x32x16_bf16(Ahi[ks], Bhi[ks], acc, 0, 0, 0);
      acc = __builtin_amdgcn_mfma_f32_32x32x16_bf16(Ahi[ks], Blo[ks], acc, 0, 0, 0);
      acc = __builtin_amdgcn_mfma_f32_32x32x16_bf16(Alo[ks], Bhi[ks], acc, 0, 0, 0);
    }
    const int m = m0 + col;
    const float sm = sqb[m];
    #pragma unroll
    for (int h = 0; h < 8; h++) {
      const int rw0 = ((2 * h) & 3) + 8 * ((2 * h) >> 2) + hoff;
      const int rw1 = ((2 * h + 1) & 3) + 8 * ((2 * h + 1) >> 2) + hoff;
      float d0 = fmaxf(sqn_r[2 * h] + sm - 2.0f * acc[2 * h], 0.f);
      float d1 = fmaxf(sqn_r[2 * h + 1] + sm - 2.0f * acc[2 * h + 1], 0.f);
      unsigned int k0 = __float_as_uint(d0) >> 15;  // fits 16 bits
      unsigned int k1 = __float_as_uint(d1) >> 15;
      if (m == n_base + rw0) k0 = 0xFFFFu;  // self exclusion
      if (m == n_base + rw1) k1 = 0xFFFFu;
      kmin[2 * h] = min(kmin[2 * h], k0);
      kmin[2 * h + 1] = min(kmin[2 * h + 1], k1);
      kpk[j][h] = k0 | (k1 << 16);
    }
  }

  // per-row min: reduce over 32 col-lanes (row lives in one half), atomicMin
  #pragma unroll
  for (int e = 0; e < 16; e++) {
    unsigned int km = kmin[e];
    #pragma unroll
    for (int d2 = 1; d2 < 32; d2 <<= 1)
      km = min(km, (unsigned int)__shfl_xor((int)km, d2, 64));
    if (col == 0)
      atomicMin(&rowminS[(e & 3) + 8 * (e >> 2) + hoff], km);
  }
  __syncthreads();

  // ---- pass 2: histogram bins (key-rowmin)>>1, window 256 quanta ----
  unsigned int rmin[16];
  #pragma unroll
  for (int e = 0; e < 16; e++)
    rmin[e] = rowminS[(e & 3) + 8 * (e >> 2) + hoff];
  #pragma unroll
  for (int j = 0; j < 8; ++j) {
    #pragma unroll
    for (int h = 0; h < 8; h++) {
      const int rw0 = ((2 * h) & 3) + 8 * ((2 * h) >> 2) + hoff;
      const int rw1 = ((2 * h + 1) & 3) + 8 * ((2 * h + 1) >> 2) + hoff;
      unsigned int pk = kpk[j][h];
      unsigned int r0 = (pk & 0xFFFFu) - rmin[2 * h];
      unsigned int r1 = (pk >> 16) - rmin[2 * h + 1];
      if (r0 < 256u) atomicAdd(&histS[rw0 * 129 + (r0 >> 1)], 1u);
      if (r1 < 256u) atomicAdd(&histS[rw1 * 129 + (r1 >> 1)], 1u);
    }
  }
  __syncthreads();

  // ---- pass 3: per-row threshold (wave w owns rows 8w..8w+7) ----
  #pragma unroll
  for (int i = 0; i < 8; ++i) {
    int rr = 8 * w + i;
    unsigned int h0 = histS[rr * 129 + 2 * l], h1 = histS[rr * 129 + 2 * l + 1];
    unsigned int ls = h0 + h1, cum = ls;
    #pragma unroll
    for (int d2 = 1; d2 < 64; d2 <<= 1) {
      unsigned int o = (unsigned int)__shfl_up((int)cum, d2, 64);
      cum += (l >= d2) ? o : 0u;
    }
    unsigned long long bal = __ballot(cum >= (unsigned int)Kk);
    if (bal != 0ull) {
      int f = __ffsll(bal) - 1;
      unsigned int cumf = (unsigned int)__shfl((int)cum, f, 64);
      unsigned int h1f = (unsigned int)__shfl((int)h1, f, 64);
      int bstar = (cumf - h1f >= (unsigned int)Kk) ? 2 * f : 2 * f + 1;
      // bin top rel = 2*bstar+1; +2 margin (approx keys + merge)
      if (l == 0) hcS[rr] = rowminS[rr] + 2u * (unsigned int)bstar + 3u;
    } else {
      if (l == 0) { hcS[rr] = 0xFFFFFFFFu; atomicOr(&fbS, 1u); }
    }
  }
  __syncthreads();

  // ---- level-2 fallback (rare): window 2048 quanta, bins rel>>4 ----
  if (fbS) {
    #pragma unroll
    for (int i = 0; i < 16; i++) {
      int idx = t + 256 * i;
      if (hcS[idx / 129] == 0xFFFFFFFFu) histS[idx] = 0u;
    }
    if (t < 32 && hcS[(4096 + t) / 129] == 0xFFFFFFFFu) histS[4096 + t] = 0u;
    __syncthreads();
    #pragma unroll
    for (int j = 0; j < 8; ++j) {
      #pragma unroll
      for (int h = 0; h < 8; h++) {
        const int rw0 = ((2 * h) & 3) + 8 * ((2 * h) >> 2) + hoff;
        const int rw1 = ((2 * h + 1) & 3) + 8 * ((2 * h + 1) >> 2) + hoff;
        unsigned int pk = kpk[j][h];
        if (hcS[rw0] == 0xFFFFFFFFu) {
          unsigned int r0 = (pk & 0xFFFFu) - rmin[2 * h];
          if (r0 < 2048u) atomicAdd(&histS[rw0 * 129 + (r0 >> 4)], 1u);
        }
        if (hcS[rw1] == 0xFFFFFFFFu) {
          unsigned int r1 = (pk >> 16) - rmin[2 * h + 1];
          if (r1 < 2048u) atomicAdd(&histS[rw1 * 129 + (r1 >> 4)], 1u);
        }
      }
    }
    __syncthreads();
    #pragma unroll
    for (int i = 0; i < 8; ++i) {
      int rr = 8 * w + i;
      if (hcS[rr] == 0xFFFFFFFFu) {
        unsigned int h0 = histS[rr * 129 + 2 * l], h1 = histS[rr * 129 + 2 * l + 1];
        unsigned int ls = h0 + h1, cum = ls;
        #pragma unroll
        for (int d2 = 1; d2 < 64; d2 <<= 1) {
          unsigned int o = (unsigned int)__shfl_up((int)cum, d2, 64);
          cum += (l >= d2) ? o : 0u;
        }
        unsigned long long bal = __ballot(cum >= (unsigned int)Kk);
        if (bal != 0ull) {
          int f = __ffsll(bal) - 1;
          unsigned int cumf = (unsigned int)__shfl((int)cum, f, 64);
          unsigned int h1f = (unsigned int)__shfl((int)h1, f, 64);
          int bstar = (cumf - h1f >= (unsigned int)Kk) ? 2 * f : 2 * f + 1;
          if (l == 0) hcS[rr] = rowminS[rr] + 16u * (unsigned int)bstar + 17u;
        } else {
          if (l == 0) hcS[rr] = rowminS[rr] + 2049u;  // pathological only
        }
      }
    }
    __syncthreads();
  }

  // ---- pass 4: collect candidates from registers (cap 64/row) ----
  unsigned int hce[16];
  #pragma unroll
  for (int e = 0; e < 16; e++)
    hce[e] = hcS[(e & 3) + 8 * (e >> 2) + hoff];
  #pragma unroll
  for (int j = 0; j < 8; ++j) {
    const int m = m0w + 32 * j + col;
    #pragma unroll
    for (int h = 0; h < 8; h++) {
      const int rw0 = ((2 * h) & 3) + 8 * ((2 * h) >> 2) + hoff;
      const int rw1 = ((2 * h + 1) & 3) + 8 * ((2 * h + 1) >> 2) + hoff;
      unsigned int pk = kpk[j][h];
      if ((pk & 0xFFFFu) <= hce[2 * h]) {
        unsigned int slot = atomicAdd(&cntS[rw0], 1u);
        if (slot < 64u) candS[rw0][slot] = m;
      }
      if ((pk >> 16) <= hce[2 * h + 1]) {
        unsigned int slot = atomicAdd(&cntS[rw1], 1u);
        if (slot < 64u) candS[rw1][slot] = m;
      }
    }
  }
  __syncthreads();

  // ---- pass 5: exact fp32 re-rank, write 20-entry shortlist ----
  const float4* xb4 = (const float4*)(x + (size_t)b * Nn * Ff);
  #pragma unroll 1
  for (int i = 0; i < 8; ++i) {
    const int rr = 8 * w + i;
    const int n = n_base + rr;
    int C = (int)cntS[rr];
    if (C > 64) C = 64;
    // inactive lanes: unique sentinels (valid m after mask, huge ds;
    // unique across quarters via mq*1024+l) -> ranks form a permutation
    // of 0..63; sentinels rank last and self-filter in the merge.
    unsigned long long key64 =
        0xFFFFFFFF00000000ull | (unsigned int)(mq * 1024 + l);
    if (l < C) {
      int mI = candS[rr][l];
      const float4* xmf = xb4 + (size_t)mI * 16;
      float ds = 0.f;
      #pragma unroll
      for (int cc = 0; cc < 16; cc++) {
        float4 a = xb4[(size_t)n * 16 + cc];  // wave-uniform
        float4 bb = xmf[cc];
        float dx = a.x - bb.x, dy = a.y - bb.y, dz = a.z - bb.z,
              dw2 = a.w - bb.w;
        ds += dx * dx + dy * dy + dz * dz + dw2 * dw2;
      }
      if (mI == n) ds = FLT_MAX;  // belt-and-braces
      key64 = ((unsigned long long)__float_as_uint(ds) << 32) | (unsigned int)mI;
    }
    keyS[w][l] = key64;  // same-wave LDS: in-order, no barrier needed
    int rank = 0;
    #pragma unroll
    for (int q = 0; q < 64; q += 4) {
      rank += (keyS[w][q] < key64) + (keyS[w][q + 1] < key64) +
              (keyS[w][q + 2] < key64) + (keyS[w][q + 3] < key64);
    }
    if (rank < Kk)
      shortl[((size_t)(b * Nn + n)) * 80 + mq * 20 + rank] = key64;
  }
}

// ---------------- merge: 80 shortlist entries -> exact top-20 -> out ----
__global__ __launch_bounds__(256) void merge_kernel(
    const unsigned long long* __restrict__ shortl,
    const float* __restrict__ u, const float* __restrict__ v,
    float* __restrict__ out) {
  __shared__ int candS[4][32];
  __shared__ unsigned long long keyS[4][80];
  const int t = threadIdx.x, l = t & 63, w = t >> 6;
  const int row = blockIdx.x * 4 + w;  // flat b*N+n
  const int rowu = __builtin_amdgcn_readfirstlane(row);
  const int b = rowu >> 12;
  // 80 = 64 + 16: every lane loads entry l; lanes 0..15 also load 64+l.
  unsigned long long k0 = shortl[(size_t)rowu * 80 + l];
  unsigned long long k1 = 0xFFFFFFFFFFFFFFFFull;
  if (l < 16) k1 = shortl[(size_t)rowu * 80 + 64 + l];
  keyS[w][l] = k0;
  if (l < 16) keyS[w][64 + l] = k1;
  // all writes by this same wave -> in-order LDS, no barrier needed
  int rank0 = 0, rank1 = 0;
  #pragma unroll
  for (int q = 0; q < 80; q += 4) {
    unsigned long long e0 = keyS[w][q], e1 = keyS[w][q + 1];
    unsigned long long e2 = keyS[w][q + 2], e3 = keyS[w][q + 3];
    rank0 += (e0 < k0) + (e1 < k0) + (e2 < k0) + (e3 < k0);
    rank1 += (e0 < k1) + (e1 < k1) + (e2 < k1) + (e3 < k1);
  }
  if (rank0 < Kk) candS[w][rank0] = (int)(k0 & 0xffffffffu) & (Nn - 1);
  if (l < 16 && rank1 < Kk) candS[w][rank1] = (int)(k1 & 0xffffffffu) & (Nn - 1);
  // keys unique (distinct m per quarter; sentinels distinct) -> ranks
  // are a permutation of 0..79 -> slots 0..19 exactly filled.
  const float* vb = v + (size_t)b * Nn * Ff;
  const size_t oidx = (size_t)rowu * 64 + l;
  float uo = u[oidx];
  float vv[Kk];
  #pragma unroll
  for (int i = 0; i < Kk; i++) {
    int mI = candS[w][i];
    vv[i] = vb[(size_t)mI * 64 + l];
  }
  float vmax = vv[0];
  #pragma unroll
  for (int i = 1; i < Kk; i++) vmax = fmaxf(vmax, vv[i]);
  out[oidx] = uo + vmax;
}

// ---------------- R2 fallback knn (verified) ----------------
constexpr int RTF = 4;
constexpr int MTF = 64;
constexpr int TPADF = 17;
constexpr int CCAPF = 64;

__global__ __launch_bounds__(256) void knn_kernel(
    const float* __restrict__ x, const float* __restrict__ sq,
    const float* __restrict__ u, const float* __restrict__ v,
    float* __restrict__ out) {
  __shared__ __align__(16) float4 tileS[MTF * TPADF];
  __shared__ __align__(16) unsigned short keysS[RTF * Nn];
  __shared__ int candS[RTF * CCAPF];
  __shared__ int ccntS[RTF];
  const int t = threadIdx.x;
  const int l = t & 63, w = t >> 6;
  const int q = l & 15, g = l >> 4;
  const int bn0 = blockIdx.x * RTF;
  const int b = bn0 >> 12;
  const int n0 = bn0 & (Nn - 1);
  const float4* xb4 = (const float4*)(x + (size_t)b * Nn * Ff);
  const float* sqb = sq + b * Nn;
  if (t < RTF) ccntS[t] = 0;
  float4 xnq[RTF][4];
  #pragma unroll
  for (int r = 0; r < RTF; r++)
    #pragma unroll
    for (int c = 0; c < 4; c++) xnq[r][c] = xb4[(n0 + r) * 16 + 4 * g + c];
  const float sn = sqb[n0 + g];
  const int selfm = n0 + g;
  for (int T = 0; T < Nn / MTF; ++T) {
    __syncthreads();
    #pragma unroll
    for (int i = 0; i < 4; i++) {
      int f = t + 256 * i;
      tileS[(f >> 4) * TPADF + (f & 15)] = xb4[T * 1024 + f];
    }
    __syncthreads();
    const int mrow = 16 * w + q;
    const float4* xmp = &tileS[mrow * TPADF + 4 * g];
    float4 xm0 = xmp[0], xm1 = xmp[1], xm2 = xmp[2], xm3 = xmp[3];
    float dot[RTF];
    #pragma unroll
    for (int r = 0; r < RTF; r++) {
      float4 a0 = xnq[r][0], a1 = xnq[r][1], a2 = xnq[r][2], a3 = xnq[r][3];
      dot[r] = a0.x * xm0.x + a0.y * xm0.y + a0.z * xm0.z + a0.w * xm0.w +
               a1.x * xm1.x + a1.y * xm1.y + a1.z * xm1.z + a1.w * xm1.w +
               a2.x * xm2.x + a2.y * xm2.y + a2.z * xm2.z + a2.w * xm2.w +
               a3.x * xm3.x + a3.y * xm3.y + a3.z * xm3.z + a3.w * xm3.w;
    }
    #pragma unroll
    for (int r = 0; r < RTF; r++) {
      dot[r] += __shfl_xor(dot[r], 16, 64);
      dot[r] += __shfl_xor(dot[r], 32, 64);
    }
    float dg = (g == 0) ? dot[0] : (g == 1) ? dot[1] : (g == 2) ? dot[2] : dot[3];
    int m = T * MTF + mrow;
    float d = fmaxf(fmaf(-2.f, dg, sqb[m] + sn), 0.f);
    unsigned int key = __float_as_uint(d) >> 15;
    if (m == selfm) key = 0xFFFFu;
    keysS[g * Nn + m] = (unsigned short)key;
  }
  __syncthreads();
  const unsigned int* kp = (const unsigned int*)&keysS[w * Nn];
  int lo = -1, hi = 65535, cntHi = Nn;
  while (cntHi > 48 && hi - lo > 1) {
    int mid = (lo + hi) >> 1;
    unsigned int midu = (unsigned int)mid;
    int c = 0;
    #pragma unroll
    for (int cc = 0; cc < 8; ++cc) {
      int rc = (cc + l) & 7;
      uint4 k4 = *(const uint4*)(kp + l * 32 + rc * 4);
      c += ((k4.x & 0xffffu) <= midu) + ((k4.x >> 16) <= midu);
      c += ((k4.y & 0xffffu) <= midu) + ((k4.y >> 16) <= midu);
      c += ((k4.z & 0xffffu) <= midu) + ((k4.z >> 16) <= midu);
      c += ((k4.w & 0xffffu) <= midu) + ((k4.w >> 16) <= midu);
    }
    #pragma unroll
    for (int d2 = 1; d2 < 64; d2 <<= 1) c += __shfl_xor(c, d2, 64);
    if (c >= Kk) { hi = mid; cntHi = c; } else { lo = mid; }
  }
  {
    unsigned int hu = (unsigned int)hi;
    #pragma unroll
    for (int cc = 0; cc < 8; ++cc) {
      int rc = (cc + l) & 7;
      uint4 k4 = *(const uint4*)(kp + l * 32 + rc * 4);
      unsigned int ks[4] = {k4.x, k4.y, k4.z, k4.w};
      #pragma unroll
      for (int uu = 0; uu < 4; ++uu) {
        #pragma unroll
        for (int hh = 0; hh < 2; ++hh) {
          unsigned int kvv = hh ? (ks[uu] >> 16) : (ks[uu] & 0xffffu);
          if (kvv <= hu) {
            int slot = atomicAdd(&ccntS[w], 1);
            if (slot < CCAPF) candS[w * CCAPF + slot] = l * 64 + (rc * 4 + uu) * 2 + hh;
          }
        }
      }
    }
  }
  __syncthreads();
  const int n = n0 + w;
  const int C = min(cntHi, CCAPF);
  unsigned long long key64 = ~0ULL;
  if (l < C) {
    int mI = candS[w * CCAPF + l];
    const float4* xmf = xb4 + mI * 16;
    float ds = 0.f;
    #pragma unroll
    for (int c = 0; c < 16; c++) {
      float4 a = xb4[n * 16 + c];
      float4 bb = xmf[c];
      float dx = a.x - bb.x, dy = a.y - bb.y, dz = a.z - bb.z, dw2 = a.w - bb.w;
      ds += dx * dx + dy * dy + dz * dz + dw2 * dw2;
    }
    key64 = ((unsigned long long)__float_as_uint(ds) << 32) | (unsigned int)mI;
  }
  float vmax = -FLT_MAX;
  const float* vb = v + (size_t)b * Nn * Ff;
  #pragma unroll
  for (int it = 0; it < Kk; ++it) {
    unsigned long long kmin = key64;
    #pragma unroll
    for (int d2 = 1; d2 < 64; d2 <<= 1) {
      unsigned long long o =
          (unsigned long long)__shfl_xor((long long)kmin, d2, 64);
      kmin = (o < kmin) ? o : kmin;
    }
    int mI = (int)(kmin & 0xffffffffu) & (Nn - 1);
    vmax = fmaxf(vmax, vb[(size_t)mI * 64 + l]);
    if (key64 == kmin) key64 = ~0ULL;
  }
  const size_t oidx = (size_t)(bn0 + w) * 64 + l;
  out[oidx] = u[oidx] + vmax;
}

extern "C" void kernel_launch(void* const* d_in, const int* in_sizes, int n_in,
                              void* d_out, int out_size, void* d_ws,
                              size_t ws_size, hipStream_t stream) {
  const float* x = (const float*)d_in[0];
  const float* W = (const float*)d_in[1];
  const float* bvec = (const float*)d_in[2];
  float* u = (float*)d_ws;                           // 4 MB
  float* v = u + (size_t)Bb * Nn * Ff;               // 4 MB
  float* sq = v + (size_t)Bb * Nn * Ff;              // 64 KB
  unsigned short* xhi = (unsigned short*)(sq + (size_t)Bb * Nn);  // 2 MB
  unsigned short* xlo = xhi + (size_t)Bb * Nn * Ff;               // 2 MB
  unsigned long long* shortl = (unsigned long long*)(xlo + (size_t)Bb * Nn * Ff);  // 10.5 MB
  float* out = (float*)d_out;
  const size_t need = (size_t)Bb * Nn * Ff * 4 * 2 + (size_t)Bb * Nn * 4 +
                      (size_t)Bb * Nn * Ff * 2 * 2 +
                      (size_t)Bb * Nn * 80 * 8;  // u,v,sq,xhi,xlo,shortl

  uv_kernel2<<<Bb * Nn / RT1, 256, 0, stream>>>(x, W, bvec, u, v, sq, xhi, xlo);
  if (ws_size >= need) {
    // 4 batches x 128 n-tiles x 4 m-quarters = 2048 blocks x 256 threads
    quarter_knn_kernel<<<Bb * Nn / 8, 256, 0, stream>>>(x, xhi, xlo, sq, shortl);
    merge_kernel<<<Bb * Nn / 4, 256, 0, stream>>>(shortl, u, v, out);
  } else {
    knn_kernel<<<Bb * Nn / RTF, 256, 0, stream>>>(x, sq, u, v, out);
  }
}

// Round 8
// 250.129 us; speedup vs baseline: 1.3591x; 1.3591x over previous
//
#include <hip/hip_runtime.h>
#include <float.h>

// EdgeConv: B=4, N=4096, Fin=64, Fout=64, K=20
// out[b,n,o] = u[b,n,o] + max_{m in knn20(n)} v[b,m,o]
//   u = x.(W1-W2)^T + bias ; v = x.W2^T
// knn on d = sq[n] + sq[m] - 2 x_n.x_m (>=0), self excluded.
//
// R14: fusion with keys in LDS. Measured law (R10/R12/R13): MFMA kernels
// get a hard 128-VGPR cap from the toolchain regardless of
// __launch_bounds__, so per-lane key arrays (64 VGPRs) always spill
// (~68 MB scratch each attempt). Fix: the MFMA sweep writes keys to LDS
// keyL[32][520] (33 KB, padded: row stride 260 dw == 4 mod 32 ->
// conflict-free), register load = A-frags + transient B + acc ~ 110.
// Chunk = 32 rows x 512 m, grid 4096, 256 thr, ~48 KB LDS -> 3 blk/CU.
// Selection per (row,chunk): rowmin -> packed 128-bin hist (2 bins/u32,
// u16 halves can't overflow at <=512 counts) -> threshold (R13 logic,
// level-2 fallback) -> collect (key16<<16|m) u32 cands <= hc (cap 48)
// -> 48-entry shortlist. NO exact rerank here (avoids 8x x-gather
// blowup). merge = R8's proven select on 384 u32/row: min -> hist ->
// threshold(+1) -> ballot-compact -> exact-fp32 rerank -> rank top-20
// -> v-gather -> out. Union of per-chunk approx-top-48 covers the true
// top-20 (a true member has approx rank <~20 in its chunk); final 20 by
// exact fp32 -> output identical to R8/R9. Keys HBM: 252 MB -> 50 MB.

constexpr int Bb = 4, Nn = 4096, Ff = 64, Kk = 20;

typedef __attribute__((ext_vector_type(8))) short bf16x8;
typedef __attribute__((ext_vector_type(16))) float f32x16;

__device__ inline unsigned int bf16rn(float f) {
  unsigned int u = __float_as_uint(f);
  return (u + 0x7fffu + ((u >> 16) & 1u)) >> 16;
}

// ---------------- K1: u, v, sq, xhi, xlo (swizzled) ----------------
constexpr int RT1 = 16;  // rows per block

__global__ __launch_bounds__(256) void uv_kernel2(
    const float* __restrict__ x, const float* __restrict__ W,
    const float* __restrict__ bvec, float* __restrict__ u,
    float* __restrict__ v, float* __restrict__ sq,
    unsigned short* __restrict__ xhi, unsigned short* __restrict__ xlo) {
  __shared__ __align__(16) float4 Ws[64 * 33];   // W row o at granules [33o,33o+32)
  __shared__ __align__(16) float4 xs[RT1 * 16];  // x row r at [16r..)
  const int t = threadIdx.x, l = t & 63, w = t >> 6;
  const int bn0 = blockIdx.x * RT1;
  #pragma unroll
  for (int i = 0; i < 8; i++) {
    int f = t + 256 * i;  // f4 index into W (64 rows x 32 f4)
    Ws[(f >> 5) * 33 + (f & 31)] = ((const float4*)W)[f];
  }
  xs[t] = ((const float4*)x)[bn0 * 16 + t];
  __syncthreads();
  // bf16 hi/lo split -> MFMA-fragment-swizzled layout
  #pragma unroll
  for (int i = 0; i < 4; i++) {
    int idx = t + 256 * i;   // 0..1023 within block's 16 rows
    int nloc = idx >> 6;     // row within block
    int k = idx & 63;        // channel
    float val = ((const float*)xs)[idx];
    unsigned int hb = bf16rn(val);
    float fhi = __uint_as_float(hb << 16);
    unsigned int lb = bf16rn(val - fhi);
    int ng = bn0 + nloc;  // global flat row (batch-local swizzle folds in)
    size_t flat = ((size_t)(ng >> 5) << 11) + ((size_t)(k >> 4) << 9) +
                  ((size_t)((k >> 3) & 1) << 8) + ((size_t)(ng & 31) << 3) +
                  (size_t)(k & 7);
    xhi[flat] = (unsigned short)hb;
    xlo[flat] = (unsigned short)lb;
  }
  // sq for rows 4w..4w+3
  #pragma unroll
  for (int i = 0; i < 4; i++) {
    int r = 4 * w + i;
    float val = ((const float*)&xs[r * 16])[l];
    float s = val * val;
    #pragma unroll
    for (int d = 32; d; d >>= 1) s += __shfl_xor(s, d, 64);
    if (l == 0) sq[bn0 + r] = s;
  }
  const int o = l;
  float ua[4] = {0.f, 0.f, 0.f, 0.f}, va[4] = {0.f, 0.f, 0.f, 0.f};
  #pragma unroll
  for (int c = 0; c < 16; c++) {
    float4 w1 = Ws[o * 33 + c];
    float4 w2 = Ws[o * 33 + 16 + c];
    float4 wd;
    wd.x = w1.x - w2.x; wd.y = w1.y - w2.y;
    wd.z = w1.z - w2.z; wd.w = w1.w - w2.w;
    #pragma unroll
    for (int i = 0; i < 4; i++) {
      float4 xv = xs[(4 * w + i) * 16 + c];
      ua[i] += xv.x * wd.x + xv.y * wd.y + xv.z * wd.z + xv.w * wd.w;
      va[i] += xv.x * w2.x + xv.y * w2.y + xv.z * w2.z + xv.w * w2.w;
    }
  }
  float bo = bvec[o];
  #pragma unroll
  for (int i = 0; i < 4; i++) {
    size_t row = (size_t)(bn0 + 4 * w + i);
    u[row * 64 + o] = ua[i] + bo;
    v[row * 64 + o] = va[i];
  }
}

// ---------------- fused chunk kernel: keys in LDS, u32 shortlist --------
// Grid 4096 (= Bb * 128 n-tiles * 8 m-chunks). Block 256 thr = 4 waves.
// Wave w: m in [chunk_base + 128w .. +128) over 4 j-tiles of 32.
// C/D: col=lane&31, row=(reg&3)+8*(reg>>2)+4*(lane>>5) [m74/m101].
// NO per-lane key arrays (128-VGPR cap, measured R10/R12/R13).

constexpr int CCAP = 48;  // candidates per (row, chunk)

__global__ __launch_bounds__(256) void chunk_knn_kernel(
    const unsigned short* __restrict__ xhi,
    const unsigned short* __restrict__ xlo, const float* __restrict__ sq,
    unsigned int* __restrict__ shortl) {
  __shared__ unsigned short keyL[32 * 520];   // 33.3 KB, stride 260 dw (==4 mod 32)
  __shared__ unsigned int histS[32 * 65];     // 128 bins packed 2/u32, stride 65
  __shared__ unsigned int candS[32 * CCAP];   // 6 KB
  __shared__ unsigned int rowminS[32];
  __shared__ unsigned int cntS[32];
  __shared__ unsigned int hcS[32];
  __shared__ unsigned int fbS;

  const int t = threadIdx.x, l = t & 63, w = t >> 6;  // w in [0,4)
  const int blk = blockIdx.x;        // 0..4095
  const int b = blk >> 10;           // batch
  const int r = blk & 1023;
  const int n_base = (r >> 3) * 32;
  const int mc = r & 7;
  const int chunk_base = mc * 512;
  const int m0w = chunk_base + w * 128;
  const int col = l & 31, hoff = (l >> 5) * 4;

  // ---- init LDS ----
  if (t < 32) { rowminS[t] = 0xFFFFFFFFu; cntS[t] = 0u; }
  if (t == 0) fbS = 0u;
  #pragma unroll
  for (int i = 0; i < 9; i++) {
    int idx = t + 256 * i;
    if (idx < 32 * 65) histS[idx] = 0u;
  }
  #pragma unroll
  for (int i = 0; i < 6; i++) candS[t + 256 * i] = 0xFFFFFFFFu;  // sentinels

  const unsigned short* xhb = xhi + (size_t)b * Nn * Ff;
  const unsigned short* xlb = xlo + (size_t)b * Nn * Ff;
  const float* sqb = sq + b * Nn;

  // A fragments (32 rows x 64 ch, hi/lo) — same swizzled layout as R9 K2
  bf16x8 Ahi[4], Alo[4];
  #pragma unroll
  for (int ks = 0; ks < 4; ks++) {
    size_t off = ((size_t)((n_base >> 5) * 4 + ks) << 9) + ((size_t)l << 3);
    Ahi[ks] = *(const bf16x8*)(xhb + off);
    Alo[ks] = *(const bf16x8*)(xlb + off);
  }
  float sqn_r[16];
  #pragma unroll
  for (int e = 0; e < 16; e++)
    sqn_r[e] = sqb[n_base + (e & 3) + 8 * (e >> 2) + hoff];
  __syncthreads();  // LDS init visible

  // ---- pass 1: MFMA sweep -> keys straight to LDS (no reg arrays) ----
  unsigned int kmin[16];
  #pragma unroll
  for (int e = 0; e < 16; e++) kmin[e] = 0xFFFFFFFFu;

  #pragma unroll
  for (int j = 0; j < 4; ++j) {
    const int m0 = m0w + 32 * j;
    const int mblk = m0 >> 5;
    bf16x8 Bhi[4], Blo[4];
    #pragma unroll
    for (int ks = 0; ks < 4; ks++) {
      size_t off = ((size_t)(mblk * 4 + ks) << 9) + ((size_t)l << 3);
      Bhi[ks] = *(const bf16x8*)(xhb + off);
      Blo[ks] = *(const bf16x8*)(xlb + off);
    }
    f32x16 acc = {0.f, 0.f, 0.f, 0.f, 0.f, 0.f, 0.f, 0.f,
                  0.f, 0.f, 0.f, 0.f, 0.f, 0.f, 0.f, 0.f};
    #pragma unroll
    for (int ks = 0; ks < 4; ks++) {
      acc = __builtin_amdgcn_mfma_f32_32x32x16_bf16(Ahi[ks], Bhi[ks], acc, 0, 0, 0);
      acc = __builtin_amdgcn_mfma_f32_32x32x16_bf16(Ahi[ks], Blo[ks], acc, 0, 0, 0);
      acc = __builtin_amdgcn_mfma_f32_32x32x16_bf16(Alo[ks], Bhi[ks], acc, 0, 0, 0);
    }
    const int m = m0 + col;
    const int ml = m - chunk_base;  // [0,512)
    const float sm = sqb[m];
    #pragma unroll
    for (int h = 0; h < 8; h++) {
      const int rw0 = ((2 * h) & 3) + 8 * ((2 * h) >> 2) + hoff;
      const int rw1 = ((2 * h + 1) & 3) + 8 * ((2 * h + 1) >> 2) + hoff;
      float d0 = fmaxf(sqn_r[2 * h] + sm - 2.0f * acc[2 * h], 0.f);
      float d1 = fmaxf(sqn_r[2 * h + 1] + sm - 2.0f * acc[2 * h + 1], 0.f);
      unsigned int k0 = __float_as_uint(d0) >> 15;  // fits 16 bits
      unsigned int k1 = __float_as_uint(d1) >> 15;
      if (m == n_base + rw0) k0 = 0xFFFFu;  // self exclusion
      if (m == n_base + rw1) k1 = 0xFFFFu;
      kmin[2 * h] = min(kmin[2 * h], k0);
      kmin[2 * h + 1] = min(kmin[2 * h + 1], k1);
      keyL[rw0 * 520 + ml] = (unsigned short)k0;
      keyL[rw1 * 520 + ml] = (unsigned short)k1;
    }
  }

  // per-row min: reduce over 32 col-lanes, atomicMin
  #pragma unroll
  for (int e = 0; e < 16; e++) {
    unsigned int km = kmin[e];
    #pragma unroll
    for (int d2 = 1; d2 < 32; d2 <<= 1)
      km = min(km, (unsigned int)__shfl_xor((int)km, d2, 64));
    if (col == 0)
      atomicMin(&rowminS[(e & 3) + 8 * (e >> 2) + hoff], km);
  }
  __syncthreads();  // keyL + rowmin visible

  // ---- pass 2: histogram from LDS keys ----
  // thread t: row = t>>3, reads 32 u32 (stride-8 interleave: <=2-way banks)
  const int hrow = t >> 3;
  const unsigned int* keyrow = (const unsigned int*)keyL + hrow * 260;
  const unsigned int rm = rowminS[hrow];
  #pragma unroll
  for (int i = 0; i < 32; i++) {
    int idx = (t & 7) + 8 * i;
    unsigned int kk = keyrow[idx];
    unsigned int r0 = (kk & 0xFFFFu) - rm;
    unsigned int r1 = (kk >> 16) - rm;
    // bins of 2 quanta, packed 2 bins/u32 (u16 halves; counts <=512)
    if (r0 < 256u)
      atomicAdd(&histS[hrow * 65 + (r0 >> 2)], ((r0 >> 1) & 1) ? 0x10000u : 1u);
    if (r1 < 256u)
      atomicAdd(&histS[hrow * 65 + (r1 >> 2)], ((r1 >> 1) & 1) ? 0x10000u : 1u);
  }
  __syncthreads();

  // ---- pass 3: per-row threshold (wave w owns rows 8w..8w+7) ----
  #pragma unroll
  for (int i = 0; i < 8; ++i) {
    int rr = 8 * w + i;
    unsigned int hv = histS[rr * 65 + l];  // bins 2l (lo16), 2l+1 (hi16)
    unsigned int h0 = hv & 0xFFFFu, h1 = hv >> 16;
    unsigned int ls = h0 + h1, cum = ls;
    #pragma unroll
    for (int d2 = 1; d2 < 64; d2 <<= 1) {
      unsigned int o = (unsigned int)__shfl_up((int)cum, d2, 64);
      cum += (l >= d2) ? o : 0u;
    }
    unsigned long long bal = __ballot(cum >= (unsigned int)Kk);
    if (bal != 0ull) {
      int f = __ffsll(bal) - 1;
      unsigned int cumf = (unsigned int)__shfl((int)cum, f, 64);
      unsigned int h1f = (unsigned int)__shfl((int)h1, f, 64);
      int bstar = (cumf - h1f >= (unsigned int)Kk) ? 2 * f : 2 * f + 1;
      // bin top rel = 2*bstar+1; +2 margin (approx keys + merge)
      if (l == 0) hcS[rr] = rowminS[rr] + 2u * (unsigned int)bstar + 3u;
    } else {
      if (l == 0) { hcS[rr] = 0xFFFFFFFFu; atomicOr(&fbS, 1u); }
    }
  }
  __syncthreads();

  // ---- level-2 fallback (rare): window 2048 quanta, bins rel>>4 ----
  if (fbS) {
    #pragma unroll
    for (int i = 0; i < 9; i++) {
      int idx = t + 256 * i;
      if (idx < 32 * 65 && hcS[idx / 65] == 0xFFFFFFFFu) histS[idx] = 0u;
    }
    __syncthreads();
    if (hcS[hrow] == 0xFFFFFFFFu) {
      #pragma unroll
      for (int i = 0; i < 32; i++) {
        int idx = (t & 7) + 8 * i;
        unsigned int kk = keyrow[idx];
        unsigned int r0 = (kk & 0xFFFFu) - rm;
        unsigned int r1 = (kk >> 16) - rm;
        if (r0 < 2048u)
          atomicAdd(&histS[hrow * 65 + (r0 >> 5)], ((r0 >> 4) & 1) ? 0x10000u : 1u);
        if (r1 < 2048u)
          atomicAdd(&histS[hrow * 65 + (r1 >> 5)], ((r1 >> 4) & 1) ? 0x10000u : 1u);
      }
    }
    __syncthreads();
    #pragma unroll
    for (int i = 0; i < 8; ++i) {
      int rr = 8 * w + i;
      if (hcS[rr] == 0xFFFFFFFFu) {
        unsigned int hv = histS[rr * 65 + l];
        unsigned int h0 = hv & 0xFFFFu, h1 = hv >> 16;
        unsigned int ls = h0 + h1, cum = ls;
        #pragma unroll
        for (int d2 = 1; d2 < 64; d2 <<= 1) {
          unsigned int o = (unsigned int)__shfl_up((int)cum, d2, 64);
          cum += (l >= d2) ? o : 0u;
        }
        unsigned long long bal = __ballot(cum >= (unsigned int)Kk);
        if (bal != 0ull) {
          int f = __ffsll(bal) - 1;
          unsigned int cumf = (unsigned int)__shfl((int)cum, f, 64);
          unsigned int h1f = (unsigned int)__shfl((int)h1, f, 64);
          int bstar = (cumf - h1f >= (unsigned int)Kk) ? 2 * f : 2 * f + 1;
          if (l == 0) hcS[rr] = rowminS[rr] + 16u * (unsigned int)bstar + 17u;
        } else {
          if (l == 0) hcS[rr] = rowminS[rr] + 2049u;  // pathological only
        }
      }
    }
    __syncthreads();
  }

  // ---- pass 4: collect (key16<<16 | m) candidates from LDS keys ----
  {
    const unsigned int hc = hcS[hrow];
    #pragma unroll
    for (int i = 0; i < 32; i++) {
      int idx = (t & 7) + 8 * i;
      unsigned int kk = keyrow[idx];
      unsigned int k0 = kk & 0xFFFFu, k1 = kk >> 16;
      if (k0 <= hc) {
        unsigned int slot = atomicAdd(&cntS[hrow], 1u);
        if (slot < (unsigned)CCAP)
          candS[hrow * CCAP + slot] = (k0 << 16) | (unsigned)(chunk_base + 2 * idx);
      }
      if (k1 <= hc) {
        unsigned int slot = atomicAdd(&cntS[hrow], 1u);
        if (slot < (unsigned)CCAP)
          candS[hrow * CCAP + slot] = (k1 << 16) | (unsigned)(chunk_base + 2 * idx + 1);
      }
    }
  }
  __syncthreads();

  // ---- pass 5: write 48-entry shortlist (sentinel-padded) ----
  #pragma unroll
  for (int i = 0; i < 6; i++) {
    int flat = t + 256 * i;  // 0..1535 = 32 rows x 48
    int row = flat / CCAP;
    int slot = flat - row * CCAP;
    shortl[((size_t)(b * Nn + n_base + row)) * (8 * CCAP) + mc * CCAP + slot] =
        candS[flat];
  }
}

// ---------------- merge: 384 u32/row -> exact top-20 -> out ----------
// R8's proven select structure; input is 1.5 KB/row instead of 8 KB.
__global__ __launch_bounds__(256) void merge_kernel(
    const float* __restrict__ x, const unsigned int* __restrict__ shortl,
    const float* __restrict__ u, const float* __restrict__ v,
    float* __restrict__ out) {
  __shared__ unsigned int histM[4][256];
  __shared__ int candM[4][64];
  __shared__ unsigned long long keyS[4][64];
  const int t = threadIdx.x, l = t & 63, w = t >> 6;
  const int row = blockIdx.x * 4 + w;  // flat b*N+n
  const int rowu = __builtin_amdgcn_readfirstlane(row);
  const int b = rowu >> 12, n = rowu & (Nn - 1);
  const unsigned int* sr = shortl + (size_t)rowu * (8 * CCAP);
  unsigned int e0 = sr[l], e1 = sr[64 + l], e2 = sr[128 + l];
  unsigned int e3 = sr[192 + l], e4 = sr[256 + l], e5 = sr[320 + l];

  #pragma unroll
  for (int i = 0; i < 4; i++) histM[w][4 * l + i] = 0u;

  auto countLE = [&](int mid) -> int {
    int c = (int)((e0 >> 16) <= (unsigned)mid) + (int)((e1 >> 16) <= (unsigned)mid) +
            (int)((e2 >> 16) <= (unsigned)mid) + (int)((e3 >> 16) <= (unsigned)mid) +
            (int)((e4 >> 16) <= (unsigned)mid) + (int)((e5 >> 16) <= (unsigned)mid);
    #pragma unroll
    for (int d2 = 1; d2 < 64; d2 <<= 1) c += __shfl_xor(c, d2, 64);
    return c;
  };

  // wave-wide min key16 (sentinels 0xFFFF rank last)
  unsigned int mn = min(min(min(e0 >> 16, e1 >> 16), min(e2 >> 16, e3 >> 16)),
                        min(e4 >> 16, e5 >> 16));
  #pragma unroll
  for (int d2 = 1; d2 < 64; d2 <<= 1)
    mn = min(mn, (unsigned int)__shfl_xor((int)mn, d2, 64));

  // histogram of rel = key16 - mn (window 256)
  {
    unsigned int r0 = (e0 >> 16) - mn, r1 = (e1 >> 16) - mn, r2 = (e2 >> 16) - mn;
    unsigned int r3 = (e3 >> 16) - mn, r4 = (e4 >> 16) - mn, r5 = (e5 >> 16) - mn;
    if (r0 < 256u) atomicAdd(&histM[w][r0], 1u);
    if (r1 < 256u) atomicAdd(&histM[w][r1], 1u);
    if (r2 < 256u) atomicAdd(&histM[w][r2], 1u);
    if (r3 < 256u) atomicAdd(&histM[w][r3], 1u);
    if (r4 < 256u) atomicAdd(&histM[w][r4], 1u);
    if (r5 < 256u) atomicAdd(&histM[w][r5], 1u);
  }
  unsigned int s0 = histM[w][4 * l + 0], s1 = histM[w][4 * l + 1];
  unsigned int s2 = histM[w][4 * l + 2], s3 = histM[w][4 * l + 3];
  unsigned int ls = s0 + s1 + s2 + s3;
  unsigned int cum = ls;
  #pragma unroll
  for (int d2 = 1; d2 < 64; d2 <<= 1) {
    unsigned int o = (unsigned int)__shfl_up((int)cum, d2, 64);
    cum += (l >= d2) ? o : 0u;
  }
  unsigned int excl = cum - ls;
  unsigned int c0 = excl + s0, c1 = c0 + s1, c2 = c1 + s2;
  unsigned long long bal = __ballot(cum >= (unsigned int)Kk);

  int hc;
  if (bal != 0ull) {
    int b_loc = (c0 >= (unsigned)Kk) ? 0 : (c1 >= (unsigned)Kk) ? 1
              : (c2 >= (unsigned)Kk) ? 2 : 3;
    int flane = __ffsll(bal) - 1;
    int hi_rel = __shfl(4 * l + b_loc, flane, 64);
    hc = (int)mn + hi_rel + 1;  // +1 quantum margin (approx keys)
  } else {
    // fallback: gallop + bisect (rare)
    int lo = (int)mn - 1;
    int hi = (int)mn + 64;
    if (hi > 65534) hi = 65534;
    int c = countLE(hi);
    int step = 128;
    while (c < Kk && hi < 65534) {
      lo = hi; hi += step;
      if (hi > 65534) hi = 65534;
      step <<= 1;
      c = countLE(hi);
    }
    while (c > 44 && hi - lo > 1) {
      int mid = (lo + hi) >> 1;
      int cm = countLE(mid);
      if (cm >= Kk) { hi = mid; c = cm; } else { lo = mid; }
    }
    hc = hi + 1;
  }

  // ballot compaction (6 rounds)
  int base = 0;
  {
    unsigned int es[6] = {e0, e1, e2, e3, e4, e5};
    #pragma unroll
    for (int i = 0; i < 6; i++) {
      bool p = (int)(es[i] >> 16) <= hc;
      unsigned long long m = __ballot(p);
      if (p) {
        int slot = base + __builtin_amdgcn_mbcnt_hi(
                              (unsigned int)(m >> 32),
                              __builtin_amdgcn_mbcnt_lo((unsigned int)m, 0));
        if (slot < 64) candM[w][slot] = (int)(es[i] & 0xFFFu);
      }
      base += __popcll(m);
    }
  }
  int C = base;
  if (C > 64) C = 64;

  // exact fp32 rerank (R8-proven)
  const float4* xb4 = (const float4*)(x + (size_t)b * Nn * Ff);
  unsigned long long key64 = 0xFFFFFFFF00000000ull | (unsigned int)l;
  if (l < C) {
    int mI = candM[w][l];
    const float4* xmf = xb4 + (size_t)mI * 16;
    float ds = 0.f;
    #pragma unroll
    for (int cc = 0; cc < 16; cc++) {
      float4 a = xb4[(size_t)n * 16 + cc];  // wave-uniform
      float4 bb = xmf[cc];
      float dx = a.x - bb.x, dy = a.y - bb.y, dz = a.z - bb.z, dw2 = a.w - bb.w;
      ds += dx * dx + dy * dy + dz * dz + dw2 * dw2;
    }
    if (mI == n) ds = FLT_MAX;  // belt-and-braces
    key64 = ((unsigned long long)__float_as_uint(ds) << 32) | (unsigned int)mI;
  }
  // rank-select top-20 (keys unique: distinct m; sentinels unique by l)
  keyS[w][l] = key64;
  int rank = 0;
  #pragma unroll
  for (int q = 0; q < 64; q += 4) {
    rank += (keyS[w][q] < key64) + (keyS[w][q + 1] < key64) +
            (keyS[w][q + 2] < key64) + (keyS[w][q + 3] < key64);
  }
  if (rank < Kk)
    candM[w][rank] = (int)(key64 & 0xffffffffu) & (Nn - 1);

  const float* vb = v + (size_t)b * Nn * Ff;
  const size_t oidx = (size_t)rowu * 64 + l;
  float uo = u[oidx];
  float vv[Kk];
  #pragma unroll
  for (int i = 0; i < Kk; i++) {
    int mI = candM[w][i];
    vv[i] = vb[(size_t)mI * 64 + l];
  }
  float vmax = vv[0];
  #pragma unroll
  for (int i = 1; i < Kk; i++) vmax = fmaxf(vmax, vv[i]);
  out[oidx] = uo + vmax;
}

// ---------------- R2 fallback knn (verified) ----------------
constexpr int RTF = 4;
constexpr int MTF = 64;
constexpr int TPADF = 17;
constexpr int CCAPF = 64;

__global__ __launch_bounds__(256) void knn_kernel(
    const float* __restrict__ x, const float* __restrict__ sq,
    const float* __restrict__ u, const float* __restrict__ v,
    float* __restrict__ out) {
  __shared__ __align__(16) float4 tileS[MTF * TPADF];
  __shared__ __align__(16) unsigned short keysS[RTF * Nn];
  __shared__ int candS[RTF * CCAPF];
  __shared__ int ccntS[RTF];
  const int t = threadIdx.x;
  const int l = t & 63, w = t >> 6;
  const int q = l & 15, g = l >> 4;
  const int bn0 = blockIdx.x * RTF;
  const int b = bn0 >> 12;
  const int n0 = bn0 & (Nn - 1);
  const float4* xb4 = (const float4*)(x + (size_t)b * Nn * Ff);
  const float* sqb = sq + b * Nn;
  if (t < RTF) ccntS[t] = 0;
  float4 xnq[RTF][4];
  #pragma unroll
  for (int r = 0; r < RTF; r++)
    #pragma unroll
    for (int c = 0; c < 4; c++) xnq[r][c] = xb4[(n0 + r) * 16 + 4 * g + c];
  const float sn = sqb[n0 + g];
  const int selfm = n0 + g;
  for (int T = 0; T < Nn / MTF; ++T) {
    __syncthreads();
    #pragma unroll
    for (int i = 0; i < 4; i++) {
      int f = t + 256 * i;
      tileS[(f >> 4) * TPADF + (f & 15)] = xb4[T * 1024 + f];
    }
    __syncthreads();
    const int mrow = 16 * w + q;
    const float4* xmp = &tileS[mrow * TPADF + 4 * g];
    float4 xm0 = xmp[0], xm1 = xmp[1], xm2 = xmp[2], xm3 = xmp[3];
    float dot[RTF];
    #pragma unroll
    for (int r = 0; r < RTF; r++) {
      float4 a0 = xnq[r][0], a1 = xnq[r][1], a2 = xnq[r][2], a3 = xnq[r][3];
      dot[r] = a0.x * xm0.x + a0.y * xm0.y + a0.z * xm0.z + a0.w * xm0.w +
               a1.x * xm1.x + a1.y * xm1.y + a1.z * xm1.z + a1.w * xm1.w +
               a2.x * xm2.x + a2.y * xm2.y + a2.z * xm2.z + a2.w * xm2.w +
               a3.x * xm3.x + a3.y * xm3.y + a3.z * xm3.z + a3.w * xm3.w;
    }
    #pragma unroll
    for (int r = 0; r < RTF; r++) {
      dot[r] += __shfl_xor(dot[r], 16, 64);
      dot[r] += __shfl_xor(dot[r], 32, 64);
    }
    float dg = (g == 0) ? dot[0] : (g == 1) ? dot[1] : (g == 2) ? dot[2] : dot[3];
    int m = T * MTF + mrow;
    float d = fmaxf(fmaf(-2.f, dg, sqb[m] + sn), 0.f);
    unsigned int key = __float_as_uint(d) >> 15;
    if (m == selfm) key = 0xFFFFu;
    keysS[g * Nn + m] = (unsigned short)key;
  }
  __syncthreads();
  const unsigned int* kp = (const unsigned int*)&keysS[w * Nn];
  int lo = -1, hi = 65535, cntHi = Nn;
  while (cntHi > 48 && hi - lo > 1) {
    int mid = (lo + hi) >> 1;
    unsigned int midu = (unsigned int)mid;
    int c = 0;
    #pragma unroll
    for (int cc = 0; cc < 8; ++cc) {
      int rc = (cc + l) & 7;
      uint4 k4 = *(const uint4*)(kp + l * 32 + rc * 4);
      c += ((k4.x & 0xffffu) <= midu) + ((k4.x >> 16) <= midu);
      c += ((k4.y & 0xffffu) <= midu) + ((k4.y >> 16) <= midu);
      c += ((k4.z & 0xffffu) <= midu) + ((k4.z >> 16) <= midu);
      c += ((k4.w & 0xffffu) <= midu) + ((k4.w >> 16) <= midu);
    }
    #pragma unroll
    for (int d2 = 1; d2 < 64; d2 <<= 1) c += __shfl_xor(c, d2, 64);
    if (c >= Kk) { hi = mid; cntHi = c; } else { lo = mid; }
  }
  {
    unsigned int hu = (unsigned int)hi;
    #pragma unroll
    for (int cc = 0; cc < 8; ++cc) {
      int rc = (cc + l) & 7;
      uint4 k4 = *(const uint4*)(kp + l * 32 + rc * 4);
      unsigned int ks[4] = {k4.x, k4.y, k4.z, k4.w};
      #pragma unroll
      for (int uu = 0; uu < 4; ++uu) {
        #pragma unroll
        for (int hh = 0; hh < 2; ++hh) {
          unsigned int kvv = hh ? (ks[uu] >> 16) : (ks[uu] & 0xffffu);
          if (kvv <= hu) {
            int slot = atomicAdd(&ccntS[w], 1);
            if (slot < CCAPF) candS[w * CCAPF + slot] = l * 64 + (rc * 4 + uu) * 2 + hh;
          }
        }
      }
    }
  }
  __syncthreads();
  const int n = n0 + w;
  const int C = min(cntHi, CCAPF);
  unsigned long long key64 = ~0ULL;
  if (l < C) {
    int mI = candS[w * CCAPF + l];
    const float4* xmf = xb4 + mI * 16;
    float ds = 0.f;
    #pragma unroll
    for (int c = 0; c < 16; c++) {
      float4 a = xb4[n * 16 + c];
      float4 bb = xmf[c];
      float dx = a.x - bb.x, dy = a.y - bb.y, dz = a.z - bb.z, dw2 = a.w - bb.w;
      ds += dx * dx + dy * dy + dz * dz + dw2 * dw2;
    }
    key64 = ((unsigned long long)__float_as_uint(ds) << 32) | (unsigned int)mI;
  }
  float vmax = -FLT_MAX;
  const float* vb = v + (size_t)b * Nn * Ff;
  #pragma unroll
  for (int it = 0; it < Kk; ++it) {
    unsigned long long kmin = key64;
    #pragma unroll
    for (int d2 = 1; d2 < 64; d2 <<= 1) {
      unsigned long long o =
          (unsigned long long)__shfl_xor((long long)kmin, d2, 64);
      kmin = (o < kmin) ? o : kmin;
    }
    int mI = (int)(kmin & 0xffffffffu) & (Nn - 1);
    vmax = fmaxf(vmax, vb[(size_t)mI * 64 + l]);
    if (key64 == kmin) key64 = ~0ULL;
  }
  const size_t oidx = (size_t)(bn0 + w) * 64 + l;
  out[oidx] = u[oidx] + vmax;
}

extern "C" void kernel_launch(void* const* d_in, const int* in_sizes, int n_in,
                              void* d_out, int out_size, void* d_ws,
                              size_t ws_size, hipStream_t stream) {
  const float* x = (const float*)d_in[0];
  const float* W = (const float*)d_in[1];
  const float* bvec = (const float*)d_in[2];
  float* u = (float*)d_ws;                           // 4 MB
  float* v = u + (size_t)Bb * Nn * Ff;               // 4 MB
  float* sq = v + (size_t)Bb * Nn * Ff;              // 64 KB
  unsigned short* xhi = (unsigned short*)(sq + (size_t)Bb * Nn);  // 2 MB
  unsigned short* xlo = xhi + (size_t)Bb * Nn * Ff;               // 2 MB
  unsigned int* shortl = (unsigned int*)(xlo + (size_t)Bb * Nn * Ff);  // 25.2 MB
  float* out = (float*)d_out;
  const size_t need = (size_t)Bb * Nn * Ff * 4 * 2 + (size_t)Bb * Nn * 4 +
                      (size_t)Bb * Nn * Ff * 2 * 2 +
                      (size_t)Bb * Nn * 8 * CCAP * 4;  // u,v,sq,xhi,xlo,shortl

  uv_kernel2<<<Bb * Nn / RT1, 256, 0, stream>>>(x, W, bvec, u, v, sq, xhi, xlo);
  if (ws_size >= need) {
    // 4 batches x 128 n-tiles x 8 m-chunks = 4096 blocks x 256 threads
    chunk_knn_kernel<<<Bb * Nn / 4, 256, 0, stream>>>(xhi, xlo, sq, shortl);
    merge_kernel<<<Bb * Nn / 4, 256, 0, stream>>>(x, shortl, u, v, out);
  } else {
    knn_kernel<<<Bb * Nn / RTF, 256, 0, stream>>>(x, sq, u, v, out);
  }
}

// Round 10
// 213.720 us; speedup vs baseline: 1.5906x; 1.1704x over previous
//
#include <hip/hip_runtime.h>
#include <float.h>

// EdgeConv: B=4, N=4096, Fin=64, Fout=64, K=20
// out[b,n,o] = u[b,n,o] + max_{m in knn20(n)} v[b,m,o]
//   u = x.(W1-W2)^T + bias ; v = x.W2^T
// knn on d = sq[n] + sq[m] - 2 x_n.x_m (>=0), self excluded.
//
// R16 = R15 resubmitted after a container-level bench failure with the
// exact signature of R5's infra flake (R5's kernel ran fine at R6).
// Re-audit found no OOB / divergent-barrier / non-termination vectors;
// saturation safety re-derived (chunk-min packs to key8=0 -> base16[c]
// >= rowmin -> saturated keys reconstruct above any realistic hc).
// Structure: R9 split pipeline (proven 148.8 us) + 8-bit key compression
// against K2's measured write wall (128 MB key16 at ~3.2 TB/s, duration
// invariant to occupancy). K2 stages key16 in LDS (33 KB padded), takes
// per-(row,512-chunk) min (O(1)/key), packs key8 = min(key16-min,255)
// -> 64 MB keys8 + 256 KB base16. key16' = base+key8 exact for
// non-saturated keys; K3 = R8's proven select on key16' + exact-fp32
// rerank -> output identical to R9.

constexpr int Bb = 4, Nn = 4096, Ff = 64, Kk = 20;

typedef __attribute__((ext_vector_type(8))) short bf16x8;
typedef __attribute__((ext_vector_type(16))) float f32x16;

__device__ inline unsigned int bf16rn(float f) {
  unsigned int u = __float_as_uint(f);
  return (u + 0x7fffu + ((u >> 16) & 1u)) >> 16;
}

// ---------------- K1: u, v, sq, xhi, xlo (swizzled) ----------------
constexpr int RT1 = 16;  // rows per block

__global__ __launch_bounds__(256) void uv_kernel2(
    const float* __restrict__ x, const float* __restrict__ W,
    const float* __restrict__ bvec, float* __restrict__ u,
    float* __restrict__ v, float* __restrict__ sq,
    unsigned short* __restrict__ xhi, unsigned short* __restrict__ xlo) {
  __shared__ __align__(16) float4 Ws[64 * 33];   // W row o at granules [33o,33o+32)
  __shared__ __align__(16) float4 xs[RT1 * 16];  // x row r at [16r..)
  const int t = threadIdx.x, l = t & 63, w = t >> 6;
  const int bn0 = blockIdx.x * RT1;
  #pragma unroll
  for (int i = 0; i < 8; i++) {
    int f = t + 256 * i;  // f4 index into W (64 rows x 32 f4)
    Ws[(f >> 5) * 33 + (f & 31)] = ((const float4*)W)[f];
  }
  xs[t] = ((const float4*)x)[bn0 * 16 + t];
  __syncthreads();
  // bf16 hi/lo split -> MFMA-fragment-swizzled layout
  #pragma unroll
  for (int i = 0; i < 4; i++) {
    int idx = t + 256 * i;   // 0..1023 within block's 16 rows
    int nloc = idx >> 6;     // row within block
    int k = idx & 63;        // channel
    float val = ((const float*)xs)[idx];
    unsigned int hb = bf16rn(val);
    float fhi = __uint_as_float(hb << 16);
    unsigned int lb = bf16rn(val - fhi);
    int ng = bn0 + nloc;  // global flat row (batch-local swizzle folds in)
    size_t flat = ((size_t)(ng >> 5) << 11) + ((size_t)(k >> 4) << 9) +
                  ((size_t)((k >> 3) & 1) << 8) + ((size_t)(ng & 31) << 3) +
                  (size_t)(k & 7);
    xhi[flat] = (unsigned short)hb;
    xlo[flat] = (unsigned short)lb;
  }
  // sq for rows 4w..4w+3
  #pragma unroll
  for (int i = 0; i < 4; i++) {
    int r = 4 * w + i;
    float val = ((const float*)&xs[r * 16])[l];
    float s = val * val;
    #pragma unroll
    for (int d = 32; d; d >>= 1) s += __shfl_xor(s, d, 64);
    if (l == 0) sq[bn0 + r] = s;
  }
  const int o = l;
  float ua[4] = {0.f, 0.f, 0.f, 0.f}, va[4] = {0.f, 0.f, 0.f, 0.f};
  #pragma unroll
  for (int c = 0; c < 16; c++) {
    float4 w1 = Ws[o * 33 + c];
    float4 w2 = Ws[o * 33 + 16 + c];
    float4 wd;
    wd.x = w1.x - w2.x; wd.y = w1.y - w2.y;
    wd.z = w1.z - w2.z; wd.w = w1.w - w2.w;
    #pragma unroll
    for (int i = 0; i < 4; i++) {
      float4 xv = xs[(4 * w + i) * 16 + c];
      ua[i] += xv.x * wd.x + xv.y * wd.y + xv.z * wd.z + xv.w * wd.w;
      va[i] += xv.x * w2.x + xv.y * w2.y + xv.z * w2.z + xv.w * w2.w;
    }
  }
  float bo = bvec[o];
  #pragma unroll
  for (int i = 0; i < 4; i++) {
    size_t row = (size_t)(bn0 + 4 * w + i);
    u[row * 64 + o] = ua[i] + bo;
    v[row * 64 + o] = va[i];
  }
}

// ---------------- K2: MFMA -> key8 + base16 (half the key bytes) --------
// Grid 4096 (= Bb * 128 n-tiles * 8 m-chunks of 512). Block 256 = 4 waves.
// Wave w: m in [chunk_base + 128w .. +128) over 4 j-tiles of 32.
// C/D: col=lane&31, row=(reg&3)+8*(reg>>2)+4*(lane>>5) [m74/m101].
// keyL stride 520 u16 = 260 dw == 4 mod 32 -> near-conflict-free.

__global__ __launch_bounds__(256) void key8_mfma_kernel(
    const unsigned short* __restrict__ xhi,
    const unsigned short* __restrict__ xlo, const float* __restrict__ sq,
    unsigned char* __restrict__ keys8, unsigned short* __restrict__ base16) {
  __shared__ unsigned short keyL[32 * 520];  // 33.3 KB
  __shared__ unsigned int cminS[32];
  const int t = threadIdx.x, l = t & 63, w = t >> 6;
  const int blk = blockIdx.x;        // 0..4095
  const int b = blk >> 10;           // batch
  const int r = blk & 1023;
  const int n_base = (r >> 3) * 32;
  const int mchunk = r & 7;
  const int chunk_base = mchunk * 512;
  const int m0w = chunk_base + w * 128;
  const int col = l & 31, hoff = (l >> 5) * 4;

  if (t < 32) cminS[t] = 0xFFFFFFFFu;

  const unsigned short* xhb = xhi + (size_t)b * Nn * Ff;
  const unsigned short* xlb = xlo + (size_t)b * Nn * Ff;
  const float* sqb = sq + b * Nn;

  bf16x8 Ahi[4], Alo[4];
  #pragma unroll
  for (int ks = 0; ks < 4; ks++) {
    size_t off = ((size_t)((n_base >> 5) * 4 + ks) << 9) + ((size_t)l << 3);
    Ahi[ks] = *(const bf16x8*)(xhb + off);
    Alo[ks] = *(const bf16x8*)(xlb + off);
  }
  float sqn_r[16];
  #pragma unroll
  for (int e = 0; e < 16; e++)
    sqn_r[e] = sqb[n_base + (e & 3) + 8 * (e >> 2) + hoff];
  __syncthreads();  // cminS init visible before atomicMin below

  unsigned int kmin[16];
  #pragma unroll
  for (int e = 0; e < 16; e++) kmin[e] = 0xFFFFFFFFu;

  #pragma unroll
  for (int j = 0; j < 4; ++j) {
    const int m0 = m0w + 32 * j;
    const int mblk = m0 >> 5;
    bf16x8 Bhi[4], Blo[4];
    #pragma unroll
    for (int ks = 0; ks < 4; ks++) {
      size_t off = ((size_t)(mblk * 4 + ks) << 9) + ((size_t)l << 3);
      Bhi[ks] = *(const bf16x8*)(xhb + off);
      Blo[ks] = *(const bf16x8*)(xlb + off);
    }
    f32x16 acc = {0.f, 0.f, 0.f, 0.f, 0.f, 0.f, 0.f, 0.f,
                  0.f, 0.f, 0.f, 0.f, 0.f, 0.f, 0.f, 0.f};
    #pragma unroll
    for (int ks = 0; ks < 4; ks++) {
      acc = __builtin_amdgcn_mfma_f32_32x32x16_bf16(Ahi[ks], Bhi[ks], acc, 0, 0, 0);
      acc = __builtin_amdgcn_mfma_f32_32x32x16_bf16(Ahi[ks], Blo[ks], acc, 0, 0, 0);
      acc = __builtin_amdgcn_mfma_f32_32x32x16_bf16(Alo[ks], Bhi[ks], acc, 0, 0, 0);
    }
    const int m = m0 + col;
    const int mloc = m - chunk_base;  // [0,512)
    const float sm = sqb[m];
    #pragma unroll
    for (int e = 0; e < 16; e++) {
      int row = (e & 3) + 8 * (e >> 2) + hoff;
      float d = fmaxf(sqn_r[e] + sm - 2.0f * acc[e], 0.f);
      unsigned int key = __float_as_uint(d) >> 15;
      if (m == n_base + row) key = 0xFFFFu;  // self exclusion
      kmin[e] = min(kmin[e], key);
      keyL[row * 520 + mloc] = (unsigned short)key;
    }
  }

  // per-(row,512-chunk) min: butterfly within 32-lane half, cross-wave atomicMin
  #pragma unroll
  for (int e = 0; e < 16; e++) {
    unsigned int km = kmin[e];
    #pragma unroll
    for (int d2 = 1; d2 < 32; d2 <<= 1)
      km = min(km, (unsigned int)__shfl_xor((int)km, d2, 64));
    if (col == 0)
      atomicMin(&cminS[(e & 3) + 8 * (e >> 2) + hoff], km);
  }
  __syncthreads();  // keyL + cminS final

  if (t < 32)
    base16[((size_t)(b * Nn + n_base + t) << 3) + mchunk] = (unsigned short)cminS[t];

  // pack pass: wave w -> rows 8w..8w+7; 512 key16 -> 128 u32 of 4x key8
  {
    const int prow = w * 8 + (l >> 3);
    const unsigned int cb = cminS[prow];
    const unsigned int* krow = (const unsigned int*)(keyL + prow * 520);
    unsigned int* o32 = (unsigned int*)keys8 +
                        ((size_t)(b * Nn + n_base + prow) << 10) + (mchunk << 7);
    #pragma unroll
    for (int i = 0; i < 16; i++) {
      int oc = (l & 7) + 8 * i;  // coalesced: lanes 0..7 contiguous u32
      unsigned int lo = krow[2 * oc], hi = krow[2 * oc + 1];
      unsigned int k0 = min((lo & 0xFFFFu) - cb, 255u);
      unsigned int k1 = min((lo >> 16) - cb, 255u);
      unsigned int k2 = min((hi & 0xFFFFu) - cb, 255u);
      unsigned int k3 = min((hi >> 16) - cb, 255u);
      o32[oc] = k0 | (k1 << 8) | (k2 << 16) | (k3 << 24);
    }
  }
}

// ---------------- K3: selection on key8 + exact top-20 + output ---------
// R8's proven select logic on key16' = base16[chunk] + key8 (exact for
// non-saturated keys). 4 uint4 loads/lane (64 B) instead of 8 (128 B).
__global__ __launch_bounds__(256) void select_kernel(
    const float* __restrict__ x, const unsigned char* __restrict__ keys8,
    const unsigned short* __restrict__ base16, const float* __restrict__ u,
    const float* __restrict__ v, float* __restrict__ out) {
  __shared__ unsigned int histM[4][256];
  __shared__ int candS[4][64];
  __shared__ unsigned long long keyS[4][64];
  const int t = threadIdx.x, l = t & 63, w = t >> 6;
  const int row = blockIdx.x * 4 + w;  // flat b*N+n
  const int rowu = __builtin_amdgcn_readfirstlane(row);
  const int b = rowu >> 12, n = rowu & (Nn - 1);
  const uint4* kr4 = (const uint4*)(keys8 + (size_t)rowu * Nn);
  uint4 kv[4];
  #pragma unroll
  for (int j = 0; j < 4; j++) kv[j] = kr4[j * 64 + l];  // coalesced 1KB/instr
  // base for kv[j]: m = (j*64+l)*16+... -> chunk512 = 2j + (l>>5)
  unsigned int bs[4];
  #pragma unroll
  for (int j = 0; j < 4; j++)
    bs[j] = base16[((size_t)rowu << 3) + 2 * j + (l >> 5)];

  #pragma unroll
  for (int i = 0; i < 4; i++) histM[w][4 * l + i] = 0u;

  auto countLE = [&](int mid) -> int {
    int c = 0;
    #pragma unroll
    for (int j = 0; j < 4; j++) {
      unsigned int a[4] = {kv[j].x, kv[j].y, kv[j].z, kv[j].w};
      unsigned int bj = bs[j];
      #pragma unroll
      for (int q = 0; q < 4; q++) {
        unsigned int xq = a[q];
        c += ((int)(bj + (xq & 255u)) <= mid) +
             ((int)(bj + ((xq >> 8) & 255u)) <= mid) +
             ((int)(bj + ((xq >> 16) & 255u)) <= mid) +
             ((int)(bj + (xq >> 24)) <= mid);
      }
    }
    #pragma unroll
    for (int d2 = 1; d2 < 64; d2 <<= 1) c += __shfl_xor(c, d2, 64);
    return c;
  };

  // wave-wide min of key16'
  unsigned int mn = 0xFFFFFFFFu;
  #pragma unroll
  for (int j = 0; j < 4; j++) {
    unsigned int a[4] = {kv[j].x, kv[j].y, kv[j].z, kv[j].w};
    unsigned int bm = 255u;
    #pragma unroll
    for (int q = 0; q < 4; q++) {
      unsigned int xq = a[q];
      bm = min(bm, min(min(xq & 255u, (xq >> 8) & 255u),
                       min((xq >> 16) & 255u, xq >> 24)));
    }
    mn = min(mn, bs[j] + bm);
  }
  #pragma unroll
  for (int d2 = 1; d2 < 64; d2 <<= 1)
    mn = min(mn, (unsigned int)__shfl_xor((int)mn, d2, 64));

  // single-pass histogram of rel = key16' - mn (window 256)
  #pragma unroll
  for (int j = 0; j < 4; j++) {
    unsigned int a[4] = {kv[j].x, kv[j].y, kv[j].z, kv[j].w};
    unsigned int bj = bs[j];
    #pragma unroll
    for (int q = 0; q < 4; q++) {
      unsigned int xq = a[q];
      unsigned int r0 = bj + (xq & 255u) - mn;
      unsigned int r1 = bj + ((xq >> 8) & 255u) - mn;
      unsigned int r2 = bj + ((xq >> 16) & 255u) - mn;
      unsigned int r3 = bj + (xq >> 24) - mn;
      if (r0 < 256u) atomicAdd(&histM[w][r0], 1u);
      if (r1 < 256u) atomicAdd(&histM[w][r1], 1u);
      if (r2 < 256u) atomicAdd(&histM[w][r2], 1u);
      if (r3 < 256u) atomicAdd(&histM[w][r3], 1u);
    }
  }
  unsigned int s0 = histM[w][4 * l + 0], s1 = histM[w][4 * l + 1];
  unsigned int s2 = histM[w][4 * l + 2], s3 = histM[w][4 * l + 3];
  unsigned int ls = s0 + s1 + s2 + s3;
  unsigned int cum = ls;
  #pragma unroll
  for (int d2 = 1; d2 < 64; d2 <<= 1) {
    unsigned int o = (unsigned int)__shfl_up((int)cum, d2, 64);
    cum += (l >= d2) ? o : 0u;
  }
  unsigned int excl = cum - ls;
  unsigned int c0 = excl + s0, c1 = c0 + s1, c2 = c1 + s2;
  unsigned long long bal = __ballot(cum >= (unsigned int)Kk);

  int hc;
  if (bal != 0ull) {
    int b_loc = (c0 >= (unsigned)Kk) ? 0 : (c1 >= (unsigned)Kk) ? 1
              : (c2 >= (unsigned)Kk) ? 2 : 3;
    int flane = __ffsll(bal) - 1;
    int hi_rel = __shfl(4 * l + b_loc, flane, 64);
    hc = (int)mn + hi_rel + 1;  // +1 quantum margin (approx keys)
  } else {
    // fallback: gallop up from min (BOUNDED), then bisect (rare)
    int lo = (int)mn - 1;
    int hi = (int)mn + 64;
    if (hi > 66046) hi = 66046;  // key16' max = 65535 + 255
    int c = countLE(hi);
    int step = 128;
    while (c < Kk && hi < 66046) {
      lo = hi;
      hi += step;
      if (hi > 66046) hi = 66046;
      step <<= 1;
      c = countLE(hi);
    }
    while (c > 44 && hi - lo > 1) {
      int mid = (lo + hi) >> 1;
      int cm = countLE(mid);
      if (cm >= Kk) { hi = mid; c = cm; } else { lo = mid; }
    }
    hc = hi + 1;
  }

  // -------- per-lane-count + scan compaction --------
  int myc = 0;
  #pragma unroll
  for (int j = 0; j < 4; j++) {
    unsigned int a[4] = {kv[j].x, kv[j].y, kv[j].z, kv[j].w};
    unsigned int bj = bs[j];
    #pragma unroll
    for (int q = 0; q < 4; q++) {
      unsigned int xq = a[q];
      myc += ((int)(bj + (xq & 255u)) <= hc) +
             ((int)(bj + ((xq >> 8) & 255u)) <= hc) +
             ((int)(bj + ((xq >> 16) & 255u)) <= hc) +
             ((int)(bj + (xq >> 24)) <= hc);
    }
  }
  int incl = myc;
  #pragma unroll
  for (int d2 = 1; d2 < 64; d2 <<= 1) {
    int o = __shfl_up(incl, d2, 64);
    incl += (l >= d2) ? o : 0;
  }
  int C = __shfl(incl, 63);
  int off = incl - myc;
  #pragma unroll
  for (int j = 0; j < 4; j++) {
    unsigned int a[4] = {kv[j].x, kv[j].y, kv[j].z, kv[j].w};
    unsigned int bj = bs[j];
    #pragma unroll
    for (int q = 0; q < 4; q++) {
      unsigned int xq = a[q];
      int mbase = ((j * 64 + l) * 4 + q) * 4;
      #pragma unroll
      for (int i = 0; i < 4; i++) {
        unsigned int byte = (xq >> (8 * i)) & 255u;
        if ((int)(bj + byte) <= hc) {
          if (off < 64) candS[w][off] = mbase + i;
          off++;
        }
      }
    }
  }
  if (C > 64) C = 64;

  // exact fp32 distance per candidate (same-wave LDS: in-order)
  const float4* xb4 = (const float4*)(x + (size_t)b * Nn * Ff);
  unsigned long long key64 = 0xFFFFFFFF00000000ull | (unsigned int)l;
  if (l < C) {
    int mI = candS[w][l];
    const float4* xmf = xb4 + (size_t)mI * 16;
    float ds = 0.f;
    #pragma unroll
    for (int cc = 0; cc < 16; cc++) {
      float4 a = xb4[(size_t)n * 16 + cc];  // wave-uniform
      float4 bb = xmf[cc];
      float dx = a.x - bb.x, dy = a.y - bb.y, dz = a.z - bb.z, dw2 = a.w - bb.w;
      ds += dx * dx + dy * dy + dz * dz + dw2 * dw2;
    }
    if (mI == n) ds = FLT_MAX;  // belt-and-braces self exclusion
    key64 = ((unsigned long long)__float_as_uint(ds) << 32) | (unsigned int)mI;
  }

  // rank-based top-20 (keys unique: distinct m; sentinels unique by l)
  keyS[w][l] = key64;
  int rank = 0;
  #pragma unroll
  for (int q = 0; q < 64; q += 4) {
    rank += (keyS[w][q] < key64) + (keyS[w][q + 1] < key64) +
            (keyS[w][q + 2] < key64) + (keyS[w][q + 3] < key64);
  }
  if (rank < Kk)
    candS[w][rank] = (int)(key64 & 0xffffffffu) & (Nn - 1);

  // 20 independent gathers + fmax tree
  const float* vb = v + (size_t)b * Nn * Ff;
  const size_t oidx = (size_t)rowu * 64 + l;
  float uo = u[oidx];
  float vv[Kk];
  #pragma unroll
  for (int i = 0; i < Kk; i++) {
    int mI = candS[w][i];
    vv[i] = vb[(size_t)mI * 64 + l];
  }
  float vmax = vv[0];
  #pragma unroll
  for (int i = 1; i < Kk; i++) vmax = fmaxf(vmax, vv[i]);
  out[oidx] = uo + vmax;
}

// ---------------- R2 fallback knn (verified) ----------------
constexpr int RTF = 4;
constexpr int MTF = 64;
constexpr int TPADF = 17;
constexpr int CCAPF = 64;

__global__ __launch_bounds__(256) void knn_kernel(
    const float* __restrict__ x, const float* __restrict__ sq,
    const float* __restrict__ u, const float* __restrict__ v,
    float* __restrict__ out) {
  __shared__ __align__(16) float4 tileS[MTF * TPADF];
  __shared__ __align__(16) unsigned short keysS[RTF * Nn];
  __shared__ int candS[RTF * CCAPF];
  __shared__ int ccntS[RTF];
  const int t = threadIdx.x;
  const int l = t & 63, w = t >> 6;
  const int q = l & 15, g = l >> 4;
  const int bn0 = blockIdx.x * RTF;
  const int b = bn0 >> 12;
  const int n0 = bn0 & (Nn - 1);
  const float4* xb4 = (const float4*)(x + (size_t)b * Nn * Ff);
  const float* sqb = sq + b * Nn;
  if (t < RTF) ccntS[t] = 0;
  float4 xnq[RTF][4];
  #pragma unroll
  for (int r = 0; r < RTF; r++)
    #pragma unroll
    for (int c = 0; c < 4; c++) xnq[r][c] = xb4[(n0 + r) * 16 + 4 * g + c];
  const float sn = sqb[n0 + g];
  const int selfm = n0 + g;
  for (int T = 0; T < Nn / MTF; ++T) {
    __syncthreads();
    #pragma unroll
    for (int i = 0; i < 4; i++) {
      int f = t + 256 * i;
      tileS[(f >> 4) * TPADF + (f & 15)] = xb4[T * 1024 + f];
    }
    __syncthreads();
    const int mrow = 16 * w + q;
    const float4* xmp = &tileS[mrow * TPADF + 4 * g];
    float4 xm0 = xmp[0], xm1 = xmp[1], xm2 = xmp[2], xm3 = xmp[3];
    float dot[RTF];
    #pragma unroll
    for (int r = 0; r < RTF; r++) {
      float4 a0 = xnq[r][0], a1 = xnq[r][1], a2 = xnq[r][2], a3 = xnq[r][3];
      dot[r] = a0.x * xm0.x + a0.y * xm0.y + a0.z * xm0.z + a0.w * xm0.w +
               a1.x * xm1.x + a1.y * xm1.y + a1.z * xm1.z + a1.w * xm1.w +
               a2.x * xm2.x + a2.y * xm2.y + a2.z * xm2.z + a2.w * xm2.w +
               a3.x * xm3.x + a3.y * xm3.y + a3.z * xm3.z + a3.w * xm3.w;
    }
    #pragma unroll
    for (int r = 0; r < RTF; r++) {
      dot[r] += __shfl_xor(dot[r], 16, 64);
      dot[r] += __shfl_xor(dot[r], 32, 64);
    }
    float dg = (g == 0) ? dot[0] : (g == 1) ? dot[1] : (g == 2) ? dot[2] : dot[3];
    int m = T * MTF + mrow;
    float d = fmaxf(fmaf(-2.f, dg, sqb[m] + sn), 0.f);
    unsigned int key = __float_as_uint(d) >> 15;
    if (m == selfm) key = 0xFFFFu;
    keysS[g * Nn + m] = (unsigned short)key;
  }
  __syncthreads();
  const unsigned int* kp = (const unsigned int*)&keysS[w * Nn];
  int lo = -1, hi = 65535, cntHi = Nn;
  while (cntHi > 48 && hi - lo > 1) {
    int mid = (lo + hi) >> 1;
    unsigned int midu = (unsigned int)mid;
    int c = 0;
    #pragma unroll
    for (int cc = 0; cc < 8; ++cc) {
      int rc = (cc + l) & 7;
      uint4 k4 = *(const uint4*)(kp + l * 32 + rc * 4);
      c += ((k4.x & 0xffffu) <= midu) + ((k4.x >> 16) <= midu);
      c += ((k4.y & 0xffffu) <= midu) + ((k4.y >> 16) <= midu);
      c += ((k4.z & 0xffffu) <= midu) + ((k4.z >> 16) <= midu);
      c += ((k4.w & 0xffffu) <= midu) + ((k4.w >> 16) <= midu);
    }
    #pragma unroll
    for (int d2 = 1; d2 < 64; d2 <<= 1) c += __shfl_xor(c, d2, 64);
    if (c >= Kk) { hi = mid; cntHi = c; } else { lo = mid; }
  }
  {
    unsigned int hu = (unsigned int)hi;
    #pragma unroll
    for (int cc = 0; cc < 8; ++cc) {
      int rc = (cc + l) & 7;
      uint4 k4 = *(const uint4*)(kp + l * 32 + rc * 4);
      unsigned int ks[4] = {k4.x, k4.y, k4.z, k4.w};
      #pragma unroll
      for (int uu = 0; uu < 4; ++uu) {
        #pragma unroll
        for (int hh = 0; hh < 2; ++hh) {
          unsigned int kvv = hh ? (ks[uu] >> 16) : (ks[uu] & 0xffffu);
          if (kvv <= hu) {
            int slot = atomicAdd(&ccntS[w], 1);
            if (slot < CCAPF) candS[w * CCAPF + slot] = l * 64 + (rc * 4 + uu) * 2 + hh;
          }
        }
      }
    }
  }
  __syncthreads();
  const int n = n0 + w;
  const int C = min(cntHi, CCAPF);
  unsigned long long key64 = ~0ULL;
  if (l < C) {
    int mI = candS[w * CCAPF + l];
    const float4* xmf = xb4 + mI * 16;
    float ds = 0.f;
    #pragma unroll
    for (int c = 0; c < 16; c++) {
      float4 a = xb4[n * 16 + c];
      float4 bb = xmf[c];
      float dx = a.x - bb.x, dy = a.y - bb.y, dz = a.z - bb.z, dw2 = a.w - bb.w;
      ds += dx * dx + dy * dy + dz * dz + dw2 * dw2;
    }
    key64 = ((unsigned long long)__float_as_uint(ds) << 32) | (unsigned int)mI;
  }
  float vmax = -FLT_MAX;
  const float* vb = v + (size_t)b * Nn * Ff;
  #pragma unroll
  for (int it = 0; it < Kk; ++it) {
    unsigned long long kmin = key64;
    #pragma unroll
    for (int d2 = 1; d2 < 64; d2 <<= 1) {
      unsigned long long o =
          (unsigned long long)__shfl_xor((long long)kmin, d2, 64);
      kmin = (o < kmin) ? o : kmin;
    }
    int mI = (int)(kmin & 0xffffffffu) & (Nn - 1);
    vmax = fmaxf(vmax, vb[(size_t)mI * 64 + l]);
    if (key64 == kmin) key64 = ~0ULL;
  }
  const size_t oidx = (size_t)(bn0 + w) * 64 + l;
  out[oidx] = u[oidx] + vmax;
}

extern "C" void kernel_launch(void* const* d_in, const int* in_sizes, int n_in,
                              void* d_out, int out_size, void* d_ws,
                              size_t ws_size, hipStream_t stream) {
  const float* x = (const float*)d_in[0];
  const float* W = (const float*)d_in[1];
  const float* bvec = (const float*)d_in[2];
  float* u = (float*)d_ws;                           // 4 MB
  float* v = u + (size_t)Bb * Nn * Ff;               // 4 MB
  float* sq = v + (size_t)Bb * Nn * Ff;              // 64 KB
  unsigned short* xhi = (unsigned short*)(sq + (size_t)Bb * Nn);  // 2 MB
  unsigned short* xlo = xhi + (size_t)Bb * Nn * Ff;               // 2 MB
  unsigned short* base16 = xlo + (size_t)Bb * Nn * Ff;            // 256 KB
  unsigned char* keys8 = (unsigned char*)(base16 + (size_t)Bb * Nn * 8);  // 64 MB
  float* out = (float*)d_out;
  const size_t need = (size_t)Bb * Nn * Ff * 4 * 2 + (size_t)Bb * Nn * 4 +
                      (size_t)Bb * Nn * Ff * 2 * 2 +
                      (size_t)Bb * Nn * 8 * 2 +      // base16
                      (size_t)Bb * Nn * Nn;          // keys8

  uv_kernel2<<<Bb * Nn / RT1, 256, 0, stream>>>(x, W, bvec, u, v, sq, xhi, xlo);
  if (ws_size >= need) {
    // 4 batches x 128 n-tiles x 8 m-chunks = 4096 blocks
    key8_mfma_kernel<<<Bb * Nn / 4, 256, 0, stream>>>(xhi, xlo, sq, keys8, base16);
    select_kernel<<<Bb * Nn / 4, 256, 0, stream>>>(x, keys8, base16, u, v, out);
  } else {
    knn_kernel<<<Bb * Nn / RTF, 256, 0, stream>>>(x, sq, u, v, out);
  }
}

// Round 11
// 159.151 us; speedup vs baseline: 2.1359x; 1.3429x over previous
//
#include <hip/hip_runtime.h>
#include <float.h>

// EdgeConv: B=4, N=4096, Fin=64, Fout=64, K=20
// out[b,n,o] = u[b,n,o] + max_{m in knn20(n)} v[b,m,o]
//   u = x.(W1-W2)^T + bias ; v = x.W2^T
// knn on d = sq[n] + sq[m] - 2 x_n.x_m (>=0), self excluded.
//
// R17: revert to the R3-proven pipeline (148.8 us: K2 key16 writer
// 49.9 us + histogram select) after key8 (R16, 213.7) failed: saturated
// bytes flooded one histogram bin (bank conflicts 59K -> 6.1M, K3
// 58->81 us) and K2's LDS staging ate the write savings. One change on
// top: K3 processes TWO rows per wave. K3 has been latency-chain-bound
// all session (VALU ~45%, HBM <20%, nothing saturated); interleaving two
// independent chains (loads/min/hist/scan/compact/rerank/gather) per
// wave overlaps the stalls. kv 2x8 uint4 = 64 VGPR + ~35 live ~= 100
// < 128 cap (kv dead before vv tail) -> no spill. Selection semantics
// identical to R8/R9 (same threshold + margin, exact fp32 rerank).

constexpr int Bb = 4, Nn = 4096, Ff = 64, Kk = 20;

typedef __attribute__((ext_vector_type(8))) short bf16x8;
typedef __attribute__((ext_vector_type(16))) float f32x16;

__device__ inline unsigned int bf16rn(float f) {
  unsigned int u = __float_as_uint(f);
  return (u + 0x7fffu + ((u >> 16) & 1u)) >> 16;
}

// ---------------- K1: u, v, sq, xhi, xlo (swizzled) ----------------
constexpr int RT1 = 16;  // rows per block

__global__ __launch_bounds__(256) void uv_kernel2(
    const float* __restrict__ x, const float* __restrict__ W,
    const float* __restrict__ bvec, float* __restrict__ u,
    float* __restrict__ v, float* __restrict__ sq,
    unsigned short* __restrict__ xhi, unsigned short* __restrict__ xlo) {
  __shared__ __align__(16) float4 Ws[64 * 33];   // W row o at granules [33o,33o+32)
  __shared__ __align__(16) float4 xs[RT1 * 16];  // x row r at [16r..)
  const int t = threadIdx.x, l = t & 63, w = t >> 6;
  const int bn0 = blockIdx.x * RT1;
  #pragma unroll
  for (int i = 0; i < 8; i++) {
    int f = t + 256 * i;  // f4 index into W (64 rows x 32 f4)
    Ws[(f >> 5) * 33 + (f & 31)] = ((const float4*)W)[f];
  }
  xs[t] = ((const float4*)x)[bn0 * 16 + t];
  __syncthreads();
  // bf16 hi/lo split -> MFMA-fragment-swizzled layout
  #pragma unroll
  for (int i = 0; i < 4; i++) {
    int idx = t + 256 * i;   // 0..1023 within block's 16 rows
    int nloc = idx >> 6;     // row within block
    int k = idx & 63;        // channel
    float val = ((const float*)xs)[idx];
    unsigned int hb = bf16rn(val);
    float fhi = __uint_as_float(hb << 16);
    unsigned int lb = bf16rn(val - fhi);
    int ng = bn0 + nloc;  // global flat row (batch-local swizzle folds in)
    size_t flat = ((size_t)(ng >> 5) << 11) + ((size_t)(k >> 4) << 9) +
                  ((size_t)((k >> 3) & 1) << 8) + ((size_t)(ng & 31) << 3) +
                  (size_t)(k & 7);
    xhi[flat] = (unsigned short)hb;
    xlo[flat] = (unsigned short)lb;
  }
  // sq for rows 4w..4w+3
  #pragma unroll
  for (int i = 0; i < 4; i++) {
    int r = 4 * w + i;
    float val = ((const float*)&xs[r * 16])[l];
    float s = val * val;
    #pragma unroll
    for (int d = 32; d; d >>= 1) s += __shfl_xor(s, d, 64);
    if (l == 0) sq[bn0 + r] = s;
  }
  const int o = l;
  float ua[4] = {0.f, 0.f, 0.f, 0.f}, va[4] = {0.f, 0.f, 0.f, 0.f};
  #pragma unroll
  for (int c = 0; c < 16; c++) {
    float4 w1 = Ws[o * 33 + c];
    float4 w2 = Ws[o * 33 + 16 + c];
    float4 wd;
    wd.x = w1.x - w2.x; wd.y = w1.y - w2.y;
    wd.z = w1.z - w2.z; wd.w = w1.w - w2.w;
    #pragma unroll
    for (int i = 0; i < 4; i++) {
      float4 xv = xs[(4 * w + i) * 16 + c];
      ua[i] += xv.x * wd.x + xv.y * wd.y + xv.z * wd.z + xv.w * wd.w;
      va[i] += xv.x * w2.x + xv.y * w2.y + xv.z * w2.z + xv.w * w2.w;
    }
  }
  float bo = bvec[o];
  #pragma unroll
  for (int i = 0; i < 4; i++) {
    size_t row = (size_t)(bn0 + 4 * w + i);
    u[row * 64 + o] = ua[i] + bo;
    v[row * 64 + o] = va[i];
  }
}

// ---------------- K2: MFMA distance keys (R3-proven, 49.9 us) ----------
// Per wave: 32 n-rows x 256 m-cols. Block = 4 waves. Grid 2048 blocks.
// C/D: col=lane&31, row=(reg&3)+8*(reg>>2)+4*(lane>>5) [m74/m101].

__global__ __launch_bounds__(256) void key_mfma_kernel(
    const unsigned short* __restrict__ xhi,
    const unsigned short* __restrict__ xlo, const float* __restrict__ sq,
    unsigned short* __restrict__ keys) {
  const int t = threadIdx.x, l = t & 63, w = t >> 6;
  const int blk = blockIdx.x;
  const int b = blk >> 9;
  const int r = blk & 511;
  const int n_base = (r >> 2) * 32;
  const int m0w = (r & 3) * 1024 + w * 256;
  const int col = l & 31, half = l >> 5;

  const unsigned short* xhb = xhi + (size_t)b * Nn * Ff;
  const unsigned short* xlb = xlo + (size_t)b * Nn * Ff;
  const float* sqb = sq + b * Nn;

  bf16x8 Ahi[4], Alo[4];
  #pragma unroll
  for (int ks = 0; ks < 4; ks++) {
    size_t off = ((size_t)((n_base >> 5) * 4 + ks) << 9) + ((size_t)l << 3);
    Ahi[ks] = *(const bf16x8*)(xhb + off);
    Alo[ks] = *(const bf16x8*)(xlb + off);
  }
  float sqn_r[16];
  #pragma unroll
  for (int e = 0; e < 16; e++) {
    int row = (e & 3) + 8 * (e >> 2) + 4 * half;
    sqn_r[e] = sqb[n_base + row];
  }

  for (int j = 0; j < 8; ++j) {
    const int m0 = m0w + 32 * j;
    const int mblk = m0 >> 5;
    bf16x8 Bhi[4], Blo[4];
    #pragma unroll
    for (int ks = 0; ks < 4; ks++) {
      size_t off = ((size_t)(mblk * 4 + ks) << 9) + ((size_t)l << 3);
      Bhi[ks] = *(const bf16x8*)(xhb + off);
      Blo[ks] = *(const bf16x8*)(xlb + off);
    }
    f32x16 acc = {0.f, 0.f, 0.f, 0.f, 0.f, 0.f, 0.f, 0.f,
                  0.f, 0.f, 0.f, 0.f, 0.f, 0.f, 0.f, 0.f};
    #pragma unroll
    for (int ks = 0; ks < 4; ks++) {
      acc = __builtin_amdgcn_mfma_f32_32x32x16_bf16(Ahi[ks], Bhi[ks], acc, 0, 0, 0);
      acc = __builtin_amdgcn_mfma_f32_32x32x16_bf16(Ahi[ks], Blo[ks], acc, 0, 0, 0);
      acc = __builtin_amdgcn_mfma_f32_32x32x16_bf16(Alo[ks], Bhi[ks], acc, 0, 0, 0);
    }
    const int m = m0 + col;
    const float sm = sqb[m];
    #pragma unroll
    for (int e = 0; e < 16; e++) {
      int row = (e & 3) + 8 * (e >> 2) + 4 * half;
      int n = n_base + row;
      float d = fmaxf(sqn_r[e] + sm - 2.0f * acc[e], 0.f);
      unsigned int key = __float_as_uint(d) >> 15;
      if (m == n) key = 0xFFFFu;
      keys[((size_t)(b * Nn + n) << 12) + m] = (unsigned short)key;
    }
  }
}

// ---------------- K3: 2 rows/wave histogram select + exact top-20 -------
// Grid 2048 blocks x 256 thr; wave w handles rows blk*8+2w, blk*8+2w+1.
// Two independent latency chains interleaved per wave.
__global__ __launch_bounds__(256) void select2_kernel(
    const float* __restrict__ x, const unsigned short* __restrict__ keys,
    const float* __restrict__ u, const float* __restrict__ v,
    float* __restrict__ out) {
  __shared__ unsigned int histS[8][256];
  __shared__ int candS[8][64];
  __shared__ unsigned long long keyS[8][64];
  const int t = threadIdx.x, l = t & 63, w = t >> 6;
  const int rowu0 = __builtin_amdgcn_readfirstlane(blockIdx.x * 8 + w * 2);
  const int rowu1 = rowu0 + 1;

  uint4 kv[2][8];
  {
    const uint4* kr0 = (const uint4*)(keys + (size_t)rowu0 * Nn);
    const uint4* kr1 = (const uint4*)(keys + (size_t)rowu1 * Nn);
    #pragma unroll
    for (int j = 0; j < 8; j++) {
      kv[0][j] = kr0[j * 64 + l];
      kv[1][j] = kr1[j * 64 + l];
    }
  }
  // zero this wave's two hist rows (same-wave LDS: in-order, no barrier)
  #pragma unroll
  for (int i = 0; i < 4; i++) {
    histS[w * 2 + 0][4 * l + i] = 0u;
    histS[w * 2 + 1][4 * l + i] = 0u;
  }

  auto countLE = [&](int rr, int mid) -> int {
    int c = 0;
    #pragma unroll
    for (int j = 0; j < 8; j++) {
      unsigned int a0 = kv[rr][j].x, a1 = kv[rr][j].y;
      unsigned int a2 = kv[rr][j].z, a3 = kv[rr][j].w;
      c += ((int)(a0 & 0xffffu) <= mid) + ((int)(a0 >> 16) <= mid);
      c += ((int)(a1 & 0xffffu) <= mid) + ((int)(a1 >> 16) <= mid);
      c += ((int)(a2 & 0xffffu) <= mid) + ((int)(a2 >> 16) <= mid);
      c += ((int)(a3 & 0xffffu) <= mid) + ((int)(a3 >> 16) <= mid);
    }
    #pragma unroll
    for (int d2 = 1; d2 < 64; d2 <<= 1) c += __shfl_xor(c, d2, 64);
    return c;
  };

  // wave-wide min per row (two butterfly chains interleaved)
  unsigned int mn[2];
  #pragma unroll
  for (int rr = 0; rr < 2; rr++) {
    unsigned int m_ = 0xffffffffu;
    #pragma unroll
    for (int j = 0; j < 8; j++) {
      unsigned int a0 = kv[rr][j].x, a1 = kv[rr][j].y;
      unsigned int a2 = kv[rr][j].z, a3 = kv[rr][j].w;
      m_ = min(m_, min(min(a0 & 0xffffu, a0 >> 16), min(a1 & 0xffffu, a1 >> 16)));
      m_ = min(m_, min(min(a2 & 0xffffu, a2 >> 16), min(a3 & 0xffffu, a3 >> 16)));
    }
    mn[rr] = m_;
  }
  #pragma unroll
  for (int d2 = 1; d2 < 64; d2 <<= 1) {
    mn[0] = min(mn[0], (unsigned int)__shfl_xor((int)mn[0], d2, 64));
    mn[1] = min(mn[1], (unsigned int)__shfl_xor((int)mn[1], d2, 64));
  }

  // histograms (window 256 above row min; rel>=256 skipped: can't matter
  // unless <20 keys that close -> gallop fallback)
  #pragma unroll
  for (int rr = 0; rr < 2; rr++) {
    #pragma unroll
    for (int j = 0; j < 8; j++) {
      unsigned int a[4] = {kv[rr][j].x, kv[rr][j].y, kv[rr][j].z, kv[rr][j].w};
      #pragma unroll
      for (int e = 0; e < 4; e++) {
        unsigned int r0 = (a[e] & 0xffffu) - mn[rr];
        unsigned int r1 = (a[e] >> 16) - mn[rr];
        if (r0 < 256u) atomicAdd(&histS[w * 2 + rr][r0], 1u);
        if (r1 < 256u) atomicAdd(&histS[w * 2 + rr][r1], 1u);
      }
    }
  }

  // prefix scan + threshold pick per row (two chains interleaved)
  unsigned int s_[2][4], ls_[2], cum_[2];
  #pragma unroll
  for (int rr = 0; rr < 2; rr++) {
    #pragma unroll
    for (int i = 0; i < 4; i++) s_[rr][i] = histS[w * 2 + rr][4 * l + i];
    ls_[rr] = s_[rr][0] + s_[rr][1] + s_[rr][2] + s_[rr][3];
    cum_[rr] = ls_[rr];
  }
  #pragma unroll
  for (int d2 = 1; d2 < 64; d2 <<= 1) {
    unsigned int o0 = (unsigned int)__shfl_up((int)cum_[0], d2, 64);
    unsigned int o1 = (unsigned int)__shfl_up((int)cum_[1], d2, 64);
    cum_[0] += (l >= d2) ? o0 : 0u;
    cum_[1] += (l >= d2) ? o1 : 0u;
  }
  int hc[2];
  #pragma unroll
  for (int rr = 0; rr < 2; rr++) {
    unsigned int excl = cum_[rr] - ls_[rr];
    unsigned int c0 = excl + s_[rr][0], c1 = c0 + s_[rr][1], c2 = c1 + s_[rr][2];
    unsigned long long bal = __ballot(cum_[rr] >= (unsigned int)Kk);
    if (bal != 0ull) {
      int b_loc = (c0 >= (unsigned)Kk) ? 0 : (c1 >= (unsigned)Kk) ? 1
                : (c2 >= (unsigned)Kk) ? 2 : 3;
      int flane = __ffsll(bal) - 1;
      int hi_rel = __shfl(4 * l + b_loc, flane, 64);
      hc[rr] = (int)mn[rr] + hi_rel + 1;  // +1 quantum margin (approx keys)
    } else {
      // fallback: gallop up from min (BOUNDED), then bisect (rare)
      int lo = (int)mn[rr] - 1;
      int hi = (int)mn[rr] + 64;
      if (hi > 65534) hi = 65534;
      int c = countLE(rr, hi);
      int step = 128;
      while (c < Kk && hi < 65534) {
        lo = hi;
        hi += step;
        if (hi > 65534) hi = 65534;
        step <<= 1;
        c = countLE(rr, hi);
      }
      while (c > 44 && hi - lo > 1) {
        int mid = (lo + hi) >> 1;
        int cm = countLE(rr, mid);
        if (cm >= Kk) { hi = mid; c = cm; } else { lo = mid; }
      }
      hc[rr] = hi + 1;
    }
  }

  // per-lane-count + scan compaction (R16-verified form), both rows
  int myc[2];
  #pragma unroll
  for (int rr = 0; rr < 2; rr++) {
    int c = 0;
    #pragma unroll
    for (int j = 0; j < 8; j++) {
      unsigned int a0 = kv[rr][j].x, a1 = kv[rr][j].y;
      unsigned int a2 = kv[rr][j].z, a3 = kv[rr][j].w;
      c += ((int)(a0 & 0xffffu) <= hc[rr]) + ((int)(a0 >> 16) <= hc[rr]);
      c += ((int)(a1 & 0xffffu) <= hc[rr]) + ((int)(a1 >> 16) <= hc[rr]);
      c += ((int)(a2 & 0xffffu) <= hc[rr]) + ((int)(a2 >> 16) <= hc[rr]);
      c += ((int)(a3 & 0xffffu) <= hc[rr]) + ((int)(a3 >> 16) <= hc[rr]);
    }
    myc[rr] = c;
  }
  int incl0 = myc[0], incl1 = myc[1];
  #pragma unroll
  for (int d2 = 1; d2 < 64; d2 <<= 1) {
    int o0 = __shfl_up(incl0, d2, 64);
    int o1 = __shfl_up(incl1, d2, 64);
    incl0 += (l >= d2) ? o0 : 0;
    incl1 += (l >= d2) ? o1 : 0;
  }
  int C[2];
  C[0] = __shfl(incl0, 63);
  C[1] = __shfl(incl1, 63);
  int off[2] = {incl0 - myc[0], incl1 - myc[1]};
  #pragma unroll
  for (int rr = 0; rr < 2; rr++) {
    int o = off[rr];
    #pragma unroll
    for (int j = 0; j < 8; j++) {
      unsigned int a[4] = {kv[rr][j].x, kv[rr][j].y, kv[rr][j].z, kv[rr][j].w};
      #pragma unroll
      for (int e = 0; e < 4; e++) {
        int base = ((j * 64 + l) * 4 + e) * 2;
        if ((int)(a[e] & 0xffffu) <= hc[rr]) {
          if (o < 64) candS[w * 2 + rr][o] = base;
          o++;
        }
        if ((int)(a[e] >> 16) <= hc[rr]) {
          if (o < 64) candS[w * 2 + rr][o] = base + 1;
          o++;
        }
      }
    }
    if (C[rr] > 64) C[rr] = 64;
  }

  // exact fp32 rerank, both rows (x-gathers interleave -> MLP)
  unsigned long long key64[2];
  #pragma unroll
  for (int rr = 0; rr < 2; rr++) {
    const int rowu = rr ? rowu1 : rowu0;
    const int b = rowu >> 12, n = rowu & (Nn - 1);
    const float4* xb4 = (const float4*)(x + (size_t)b * Nn * Ff);
    key64[rr] = 0xFFFFFFFF00000000ull | (unsigned int)l;
    if (l < C[rr]) {
      int mI = candS[w * 2 + rr][l];
      const float4* xmf = xb4 + (size_t)mI * 16;
      float ds = 0.f;
      #pragma unroll
      for (int cc = 0; cc < 16; cc++) {
        float4 a = xb4[(size_t)n * 16 + cc];  // wave-uniform
        float4 bb = xmf[cc];
        float dx = a.x - bb.x, dy = a.y - bb.y, dz = a.z - bb.z,
              dw2 = a.w - bb.w;
        ds += dx * dx + dy * dy + dz * dz + dw2 * dw2;
      }
      if (mI == n) ds = FLT_MAX;  // belt-and-braces
      key64[rr] =
          ((unsigned long long)__float_as_uint(ds) << 32) | (unsigned int)mI;
    }
    keyS[w * 2 + rr][l] = key64[rr];
  }
  // rank-select top-20 per row (keys unique: distinct m / lane sentinels)
  #pragma unroll
  for (int rr = 0; rr < 2; rr++) {
    const unsigned long long* kws = &keyS[w * 2 + rr][0];
    unsigned long long k64 = key64[rr];
    int rank = 0;
    #pragma unroll
    for (int q = 0; q < 64; q += 4) {
      rank += (kws[q] < k64) + (kws[q + 1] < k64) +
              (kws[q + 2] < k64) + (kws[q + 3] < k64);
    }
    if (rank < Kk)
      candS[w * 2 + rr][rank] = (int)(k64 & 0xffffffffu) & (Nn - 1);
  }

  // v-gathers (40 independent loads) + fmax trees + outputs
  #pragma unroll
  for (int rr = 0; rr < 2; rr++) {
    const int rowu = rr ? rowu1 : rowu0;
    const int b = rowu >> 12;
    const float* vb = v + (size_t)b * Nn * Ff;
    const size_t oidx = (size_t)rowu * 64 + l;
    float uo = u[oidx];
    float vv[Kk];
    #pragma unroll
    for (int i = 0; i < Kk; i++) {
      int mI = candS[w * 2 + rr][i];
      vv[i] = vb[(size_t)mI * 64 + l];
    }
    float vmax = vv[0];
    #pragma unroll
    for (int i = 1; i < Kk; i++) vmax = fmaxf(vmax, vv[i]);
    out[oidx] = uo + vmax;
  }
}

// ---------------- R2 fallback knn (verified) ----------------
constexpr int RTF = 4;
constexpr int MTF = 64;
constexpr int TPADF = 17;
constexpr int CCAPF = 64;

__global__ __launch_bounds__(256) void knn_kernel(
    const float* __restrict__ x, const float* __restrict__ sq,
    const float* __restrict__ u, const float* __restrict__ v,
    float* __restrict__ out) {
  __shared__ __align__(16) float4 tileS[MTF * TPADF];
  __shared__ __align__(16) unsigned short keysS[RTF * Nn];
  __shared__ int candS[RTF * CCAPF];
  __shared__ int ccntS[RTF];
  const int t = threadIdx.x;
  const int l = t & 63, w = t >> 6;
  const int q = l & 15, g = l >> 4;
  const int bn0 = blockIdx.x * RTF;
  const int b = bn0 >> 12;
  const int n0 = bn0 & (Nn - 1);
  const float4* xb4 = (const float4*)(x + (size_t)b * Nn * Ff);
  const float* sqb = sq + b * Nn;
  if (t < RTF) ccntS[t] = 0;
  float4 xnq[RTF][4];
  #pragma unroll
  for (int r = 0; r < RTF; r++)
    #pragma unroll
    for (int c = 0; c < 4; c++) xnq[r][c] = xb4[(n0 + r) * 16 + 4 * g + c];
  const float sn = sqb[n0 + g];
  const int selfm = n0 + g;
  for (int T = 0; T < Nn / MTF; ++T) {
    __syncthreads();
    #pragma unroll
    for (int i = 0; i < 4; i++) {
      int f = t + 256 * i;
      tileS[(f >> 4) * TPADF + (f & 15)] = xb4[T * 1024 + f];
    }
    __syncthreads();
    const int mrow = 16 * w + q;
    const float4* xmp = &tileS[mrow * TPADF + 4 * g];
    float4 xm0 = xmp[0], xm1 = xmp[1], xm2 = xmp[2], xm3 = xmp[3];
    float dot[RTF];
    #pragma unroll
    for (int r = 0; r < RTF; r++) {
      float4 a0 = xnq[r][0], a1 = xnq[r][1], a2 = xnq[r][2], a3 = xnq[r][3];
      dot[r] = a0.x * xm0.x + a0.y * xm0.y + a0.z * xm0.z + a0.w * xm0.w +
               a1.x * xm1.x + a1.y * xm1.y + a1.z * xm1.z + a1.w * xm1.w +
               a2.x * xm2.x + a2.y * xm2.y + a2.z * xm2.z + a2.w * xm2.w +
               a3.x * xm3.x + a3.y * xm3.y + a3.z * xm3.z + a3.w * xm3.w;
    }
    #pragma unroll
    for (int r = 0; r < RTF; r++) {
      dot[r] += __shfl_xor(dot[r], 16, 64);
      dot[r] += __shfl_xor(dot[r], 32, 64);
    }
    float dg = (g == 0) ? dot[0] : (g == 1) ? dot[1] : (g == 2) ? dot[2] : dot[3];
    int m = T * MTF + mrow;
    float d = fmaxf(fmaf(-2.f, dg, sqb[m] + sn), 0.f);
    unsigned int key = __float_as_uint(d) >> 15;
    if (m == selfm) key = 0xFFFFu;
    keysS[g * Nn + m] = (unsigned short)key;
  }
  __syncthreads();
  const unsigned int* kp = (const unsigned int*)&keysS[w * Nn];
  int lo = -1, hi = 65535, cntHi = Nn;
  while (cntHi > 48 && hi - lo > 1) {
    int mid = (lo + hi) >> 1;
    unsigned int midu = (unsigned int)mid;
    int c = 0;
    #pragma unroll
    for (int cc = 0; cc < 8; ++cc) {
      int rc = (cc + l) & 7;
      uint4 k4 = *(const uint4*)(kp + l * 32 + rc * 4);
      c += ((k4.x & 0xffffu) <= midu) + ((k4.x >> 16) <= midu);
      c += ((k4.y & 0xffffu) <= midu) + ((k4.y >> 16) <= midu);
      c += ((k4.z & 0xffffu) <= midu) + ((k4.z >> 16) <= midu);
      c += ((k4.w & 0xffffu) <= midu) + ((k4.w >> 16) <= midu);
    }
    #pragma unroll
    for (int d2 = 1; d2 < 64; d2 <<= 1) c += __shfl_xor(c, d2, 64);
    if (c >= Kk) { hi = mid; cntHi = c; } else { lo = mid; }
  }
  {
    unsigned int hu = (unsigned int)hi;
    #pragma unroll
    for (int cc = 0; cc < 8; ++cc) {
      int rc = (cc + l) & 7;
      uint4 k4 = *(const uint4*)(kp + l * 32 + rc * 4);
      unsigned int ks[4] = {k4.x, k4.y, k4.z, k4.w};
      #pragma unroll
      for (int uu = 0; uu < 4; ++uu) {
        #pragma unroll
        for (int hh = 0; hh < 2; ++hh) {
          unsigned int kvv = hh ? (ks[uu] >> 16) : (ks[uu] & 0xffffu);
          if (kvv <= hu) {
            int slot = atomicAdd(&ccntS[w], 1);
            if (slot < CCAPF) candS[w * CCAPF + slot] = l * 64 + (rc * 4 + uu) * 2 + hh;
          }
        }
      }
    }
  }
  __syncthreads();
  const int n = n0 + w;
  const int C = min(cntHi, CCAPF);
  unsigned long long key64 = ~0ULL;
  if (l < C) {
    int mI = candS[w * CCAPF + l];
    const float4* xmf = xb4 + mI * 16;
    float ds = 0.f;
    #pragma unroll
    for (int c = 0; c < 16; c++) {
      float4 a = xb4[n * 16 + c];
      float4 bb = xmf[c];
      float dx = a.x - bb.x, dy = a.y - bb.y, dz = a.z - bb.z, dw2 = a.w - bb.w;
      ds += dx * dx + dy * dy + dz * dz + dw2 * dw2;
    }
    key64 = ((unsigned long long)__float_as_uint(ds) << 32) | (unsigned int)mI;
  }
  float vmax = -FLT_MAX;
  const float* vb = v + (size_t)b * Nn * Ff;
  #pragma unroll
  for (int it = 0; it < Kk; ++it) {
    unsigned long long kmin = key64;
    #pragma unroll
    for (int d2 = 1; d2 < 64; d2 <<= 1) {
      unsigned long long o =
          (unsigned long long)__shfl_xor((long long)kmin, d2, 64);
      kmin = (o < kmin) ? o : kmin;
    }
    int mI = (int)(kmin & 0xffffffffu) & (Nn - 1);
    vmax = fmaxf(vmax, vb[(size_t)mI * 64 + l]);
    if (key64 == kmin) key64 = ~0ULL;
  }
  const size_t oidx = (size_t)(bn0 + w) * 64 + l;
  out[oidx] = u[oidx] + vmax;
}

extern "C" void kernel_launch(void* const* d_in, const int* in_sizes, int n_in,
                              void* d_out, int out_size, void* d_ws,
                              size_t ws_size, hipStream_t stream) {
  const float* x = (const float*)d_in[0];
  const float* W = (const float*)d_in[1];
  const float* bvec = (const float*)d_in[2];
  float* u = (float*)d_ws;                           // 4 MB
  float* v = u + (size_t)Bb * Nn * Ff;               // 4 MB
  float* sq = v + (size_t)Bb * Nn * Ff;              // 64 KB
  unsigned short* xhi = (unsigned short*)(sq + (size_t)Bb * Nn);  // 2 MB
  unsigned short* xlo = xhi + (size_t)Bb * Nn * Ff;               // 2 MB
  unsigned short* keys = xlo + (size_t)Bb * Nn * Ff;              // 128 MB
  float* out = (float*)d_out;
  const size_t need = (size_t)Bb * Nn * Ff * 4 * 2 + (size_t)Bb * Nn * 4 +
                      (size_t)Bb * Nn * Ff * 2 * 2 + (size_t)Bb * Nn * Nn * 2;

  uv_kernel2<<<Bb * Nn / RT1, 256, 0, stream>>>(x, W, bvec, u, v, sq, xhi, xlo);
  if (ws_size >= need) {
    // 4 batches x 128 n-tiles x 4 m-quarters = 2048 blocks
    key_mfma_kernel<<<Bb * Nn / 8, 256, 0, stream>>>(xhi, xlo, sq, keys);
    // 2048 blocks x 8 rows (2 per wave)
    select2_kernel<<<Bb * Nn / 8, 256, 0, stream>>>(x, keys, u, v, out);
  } else {
    knn_kernel<<<Bb * Nn / RTF, 256, 0, stream>>>(x, sq, u, v, out);
  }
}